// Round 12
// baseline (490.696 us; speedup 1.0000x reference)
//
#include <hip/hip_runtime.h>
#include <hip/hip_bf16.h>

constexpr int B_ = 8, N_ = 2048, K_ = 20;
constexpr float EPS_ = 1e-5f;

// ---- weight area offsets (float slots; "u" = uint32 of packed half2) ----
// mv/q/k matrices stored as MFMA A-fragments (16x16x32 f16):
// frag index ((mt*KS+ks)*64+l)*4+q -> m = mt*16+(l&15), k = ks*32+(l>>4)*8+2q
constexpr int OW1P = 0;                    // u W1 frags  mt16 ks16 = 65536u
constexpr int OWSP = OW1P + 256 * 256;     // u Ws frags  65536u
constexpr int OW2P = OWSP + 256 * 256;     // u W2 frags  mt16 ks8 = 32768u
constexpr int OWVP = OW2P + 128 * 256;     // u wv frags  mt4 ks8 = 8192u
constexpr int OWRP = OWVP + 128 * 64;      // u wr frags  mt8 ks8 = 16384u
constexpr int OWQT = OWRP + 128 * 128;     // u wq frags  mt4 ks8 = 8192u
constexpr int OWKT = OWQT + 256 * 64;      // u wk frags  8192u
constexpr int OWUT = OWKT + 256 * 64;      // f32 wu^T [256][64]
constexpr int OWET = OWUT + 256 * 64;      // f32 we NATIVE [co 128][o 64]
constexpr int OWTF = OWET + 64 * 128;      // u  wt A-frags  [mt8][ks8][l64]x4u
constexpr int OAWF = OWTF + 16384;         // u  am_w1 A-frags [mt16][ks2][l64]x4u
constexpr int OPWF = OAWF + 8192;          // u  pm_w2 A-frags [mt4][ks2][l64]x4u
constexpr int OPW1 = OPWF + 2048;          // pm_w1 [ph][3]
constexpr int OB1  = OPW1 + 192;           // mv_b1 [256]
constexpr int OBS2 = OB1 + 256;            // mv_bs + mv_b2 [256]
constexpr int OBQ  = OBS2 + 256;
constexpr int OBK  = OBQ + 64;
constexpr int OBV  = OBK + 64;
constexpr int OBU  = OBV + 64;
constexpr int OBR  = OBU + 64;             // [128]
constexpr int OBE  = OBR + 128;            // [128]
constexpr int OPB1 = OBE + 128;            // [64]
constexpr int OPSC = OPB1 + 64;
constexpr int OPSH = OPSC + 64;
constexpr int OPB2 = OPSH + 64;
constexpr int OASC = OPB2 + 64;            // [256]
constexpr int OASH = OASC + 256;
constexpr int OAB1 = OASH + 256;
constexpr int OABT = OAB1 + 256;           // [64]

// ---- workspace byte offsets (28 MiB total) ----
constexpr size_t OFFB_WF   = 0;
constexpr size_t OFFB_IDX  = (size_t)2 << 20;
constexpr size_t OFFB_Q    = (size_t)4 << 20;   // [b][n][64]
constexpr size_t OFFB_K    = (size_t)8 << 20;   // [b][n][64]
constexpr size_t OFFB_U    = (size_t)12 << 20;  // [b][n][64]
constexpr size_t OFFB_V    = (size_t)16 << 20;  // [b][n][64]
constexpr size_t OFFB_IDEN = (size_t)20 << 20;  // [b][n][128]

struct InPtrs { const float* p[38]; };

// ---- f16 helpers ----
typedef _Float16 half2_t __attribute__((ext_vector_type(2)));
typedef _Float16 f16x8_t __attribute__((ext_vector_type(8)));
typedef float    f32x4_t __attribute__((ext_vector_type(4)));

union U4H8 { uint4 u; f16x8_t h; };

__device__ __forceinline__ unsigned pkh2(float a, float b) {
  union { unsigned u; half2_t h; } x;
  x.h = half2_t{(_Float16)a, (_Float16)b};
  return x.u;
}
__device__ __forceinline__ f32x4_t mfma_16x16x32(f16x8_t a, f16x8_t b, f32x4_t c) {
  return __builtin_amdgcn_mfma_f32_16x16x32_f16(a, b, c, 0, 0, 0);
}

// ------------------------------------------------------------------
// Weight prep (unchanged from r11).
// ------------------------------------------------------------------
__global__ __launch_bounds__(256) void k_prep(InPtrs in, float* __restrict__ wf) {
  const int tid = blockIdx.x * 256 + threadIdx.x;
  const int nth = gridDim.x * 256;
  const float *mv_w1 = in.p[4], *mv_b1 = in.p[5], *mv_w2 = in.p[6], *mv_b2 = in.p[7],
              *mv_ws = in.p[8], *mv_bs = in.p[9], *wk = in.p[10], *bk = in.p[11],
              *wq = in.p[12], *bq = in.p[13], *wv = in.p[14], *bv = in.p[15],
              *wu = in.p[16], *bu = in.p[17], *pm_w1 = in.p[18], *pm_b1 = in.p[19],
              *pm_g = in.p[20], *pm_be = in.p[21], *pm_m = in.p[22], *pm_v = in.p[23],
              *pm_w2 = in.p[24], *pm_b2 = in.p[25], *am_w1 = in.p[26], *am_b1 = in.p[27],
              *am_g = in.p[28], *am_be = in.p[29], *am_m = in.p[30], *am_v = in.p[31],
              *am_wt = in.p[32], *am_bt = in.p[33], *we = in.p[34], *be = in.p[35],
              *wr = in.p[36], *br = in.p[37];

  {
    unsigned* w1f = (unsigned*)(wf + OW1P);
    for (int i = tid; i < 65536; i += nth) {
      int q = i & 3, l = (i >> 2) & 63, ks = (i >> 8) & 15, mt = i >> 12;
      int m = mt * 16 + (l & 15);
      int k = ks * 32 + ((l >> 4) << 3) + 2 * q;
      w1f[i] = pkh2(mv_w1[m * 512 + k], mv_w1[m * 512 + k + 1]);
    }
    unsigned* wsf = (unsigned*)(wf + OWSP);
    for (int i = tid; i < 65536; i += nth) {
      int q = i & 3, l = (i >> 2) & 63, ks = (i >> 8) & 15, mt = i >> 12;
      int m = mt * 16 + (l & 15);
      int k = ks * 32 + ((l >> 4) << 3) + 2 * q;
      wsf[i] = pkh2(mv_ws[m * 512 + k], mv_ws[m * 512 + k + 1]);
    }
    unsigned* w2f = (unsigned*)(wf + OW2P);
    for (int i = tid; i < 32768; i += nth) {
      int q = i & 3, l = (i >> 2) & 63, ks = (i >> 8) & 7, mt = i >> 11;
      int m = mt * 16 + (l & 15);
      int k = ks * 32 + ((l >> 4) << 3) + 2 * q;
      w2f[i] = pkh2(mv_w2[m * 256 + k], mv_w2[m * 256 + k + 1]);
    }
    unsigned* wvf = (unsigned*)(wf + OWVP);
    for (int i = tid; i < 8192; i += nth) {
      int q = i & 3, l = (i >> 2) & 63, ks = (i >> 8) & 7, mt = i >> 11;
      int m = mt * 16 + (l & 15);
      int k = ks * 32 + ((l >> 4) << 3) + 2 * q;
      wvf[i] = pkh2(wv[m * 256 + k], wv[m * 256 + k + 1]);
    }
    unsigned* wrf = (unsigned*)(wf + OWRP);
    for (int i = tid; i < 16384; i += nth) {
      int q = i & 3, l = (i >> 2) & 63, ks = (i >> 8) & 7, mt = i >> 11;
      int m = mt * 16 + (l & 15);
      int k = ks * 32 + ((l >> 4) << 3) + 2 * q;
      wrf[i] = pkh2(wr[m * 256 + k], wr[m * 256 + k + 1]);
    }
    unsigned* wqf = (unsigned*)(wf + OWQT);
    for (int i = tid; i < 8192; i += nth) {
      int q = i & 3, l = (i >> 2) & 63, ks = (i >> 8) & 7, mt = i >> 11;
      int m = mt * 16 + (l & 15);
      int k = ks * 32 + ((l >> 4) << 3) + 2 * q;
      wqf[i] = pkh2(wq[m * 256 + k], wq[m * 256 + k + 1]);
    }
    unsigned* wkf = (unsigned*)(wf + OWKT);
    for (int i = tid; i < 8192; i += nth) {
      int q = i & 3, l = (i >> 2) & 63, ks = (i >> 8) & 7, mt = i >> 11;
      int m = mt * 16 + (l & 15);
      int k = ks * 32 + ((l >> 4) << 3) + 2 * q;
      wkf[i] = pkh2(wk[m * 256 + k], wk[m * 256 + k + 1]);
    }
  }
  for (int i = tid; i < 256 * 64; i += nth) { int c = i >> 6, m = i & 63; wf[OWUT + i] = wu[m * 256 + c]; }
  for (int i = tid; i < 64 * 128; i += nth) wf[OWET + i] = we[i];  // native [co][o]

  {
    unsigned* wtf = (unsigned*)(wf + OWTF);
    for (int i = tid; i < 16384; i += nth) {
      int q = i & 3, l = (i >> 2) & 63, ks = (i >> 8) & 7, mt = i >> 11;
      int orr = mt * 16 + (l & 15);
      int c = ks * 32 + ((l >> 4) << 3) + 2 * q;
      wtf[i] = pkh2(am_wt[c * 128 + orr], am_wt[(c + 1) * 128 + orr]);
    }
  }
  {
    unsigned* awf = (unsigned*)(wf + OAWF);
    for (int i = tid; i < 8192; i += nth) {
      int q = i & 3, l = (i >> 2) & 63, ks = (i >> 8) & 1, mt = i >> 9;
      int c = mt * 16 + (l & 15);
      int o = ks * 32 + ((l >> 4) << 3) + 2 * q;
      awf[i] = pkh2(am_w1[c * 64 + o], am_w1[c * 64 + o + 1]);
    }
  }
  {
    unsigned* pwf = (unsigned*)(wf + OPWF);
    for (int i = tid; i < 2048; i += nth) {
      int q = i & 3, l = (i >> 2) & 63, ks = (i >> 8) & 1, mt = i >> 9;
      int o = mt * 16 + (l & 15);
      int ph = ks * 32 + ((l >> 4) << 3) + 2 * q;
      pwf[i] = pkh2(pm_w2[o * 64 + ph], pm_w2[o * 64 + ph + 1]);
    }
  }
  for (int i = tid; i < 192; i += nth) wf[OPW1 + i] = pm_w1[i];
  for (int i = tid; i < 256; i += nth) {
    wf[OB1 + i] = mv_b1[i];
    wf[OBS2 + i] = mv_bs[i] + mv_b2[i];
    float sc = am_g[i] / sqrtf(am_v[i] + EPS_);
    wf[OASC + i] = sc;
    wf[OASH + i] = am_be[i] - am_m[i] * sc;
    wf[OAB1 + i] = am_b1[i];
  }
  for (int i = tid; i < 64; i += nth) {
    wf[OBQ + i] = bq[i]; wf[OBK + i] = bk[i];
    wf[OBV + i] = bv[i]; wf[OBU + i] = bu[i];
    wf[OABT + i] = am_bt[i]; wf[OPB1 + i] = pm_b1[i]; wf[OPB2 + i] = pm_b2[i];
    float sc = pm_g[i] / sqrtf(pm_v[i] + EPS_);
    wf[OPSC + i] = sc;
    wf[OPSH + i] = pm_be[i] - pm_m[i] * sc;
  }
  for (int i = tid; i < 128; i += nth) { wf[OBR + i] = br[i]; wf[OBE + i] = be[i]; }
}

// ------------------------------------------------------------------
// Fused mv-MLP v3 (unchanged): all 5 mv GEMMs + q/k on MFMA.
// ------------------------------------------------------------------
__global__ __launch_bounds__(256, 2) void k_mv(const float* __restrict__ wf,
                                               const float* __restrict__ keyf,
                                               const float* __restrict__ qryf,
                                               float* __restrict__ vout,
                                               float* __restrict__ idenout,
                                               float* __restrict__ qout,
                                               float* __restrict__ kout) {
  const int b = blockIdx.y;
  const int n0 = blockIdx.x * 32;
  const int tid = threadIdx.x, lane = tid & 63, wid = tid >> 6;
  __shared__ __align__(16) char smem[49152];
  char* xsb = smem;
  char* hbb = smem + 32768;
  char* vbb = smem;

  {
    const int col = tid & 31, kq = tid >> 5;
    const int swz = (col & 7) << 4;
#pragma unroll 4
    for (int it = 0; it < 32; ++it) {
      int k2 = it * 8 + kq;
      int c = 2 * k2;
      const float* s = (c < 256) ? keyf : qryf;
      size_t base = ((size_t)b * 256 + (c & 255)) * N_ + n0 + col;
      float x0 = s[base], x1 = s[base + N_];
      *(unsigned*)(xsb + ((col * 1024 + k2 * 4) ^ swz)) = pkh2(x0, x1);
    }
  }
  __syncthreads();

  f32x4_t acch[4][2], accs[4][2];
#pragma unroll
  for (int m = 0; m < 4; ++m)
#pragma unroll
    for (int nt = 0; nt < 2; ++nt) {
      acch[m][nt] = f32x4_t{0.f, 0.f, 0.f, 0.f};
      accs[m][nt] = f32x4_t{0.f, 0.f, 0.f, 0.f};
    }
  {
    const uint4* w1f = (const uint4*)((const unsigned*)(wf + OW1P));
    const uint4* wsf = (const uint4*)((const unsigned*)(wf + OWSP));
#pragma unroll 2
    for (int ks = 0; ks < 16; ++ks) {
      U4H8 bu[2];
#pragma unroll
      for (int nt = 0; nt < 2; ++nt) {
        int col = nt * 16 + (lane & 15);
        bu[nt].u = *(const uint4*)(xsb + ((col * 1024 + ks * 64 + ((lane >> 4) << 4)) ^ ((col & 7) << 4)));
      }
#pragma unroll
      for (int m = 0; m < 4; ++m) {
        U4H8 a1, as_;
        a1.u = w1f[((wid * 4 + m) * 16 + ks) * 64 + lane];
        as_.u = wsf[((wid * 4 + m) * 16 + ks) * 64 + lane];
#pragma unroll
        for (int nt = 0; nt < 2; ++nt) {
          acch[m][nt] = mfma_16x16x32(a1.h, bu[nt].h, acch[m][nt]);
          accs[m][nt] = mfma_16x16x32(as_.h, bu[nt].h, accs[m][nt]);
        }
      }
    }
  }
#pragma unroll
  for (int m = 0; m < 4; ++m) {
    int ch0 = (wid * 4 + m) * 16 + ((lane >> 4) << 2);
    float4 b1v = *(const float4*)(wf + OB1 + ch0);
#pragma unroll
    for (int nt = 0; nt < 2; ++nt) {
      int col = nt * 16 + (lane & 15);
      float h0 = fmaxf(acch[m][nt][0] + b1v.x, 0.f);
      float h1 = fmaxf(acch[m][nt][1] + b1v.y, 0.f);
      float h2 = fmaxf(acch[m][nt][2] + b1v.z, 0.f);
      float h3 = fmaxf(acch[m][nt][3] + b1v.w, 0.f);
      uint2 p;
      p.x = pkh2(h0, h1);
      p.y = pkh2(h2, h3);
      *(uint2*)(hbb + ((col * 512 + ch0 * 2) ^ ((col & 7) << 4))) = p;
    }
  }

  {
    f32x4_t accq[2], acck[2];
#pragma unroll
    for (int nt = 0; nt < 2; ++nt) {
      accq[nt] = f32x4_t{0.f, 0.f, 0.f, 0.f};
      acck[nt] = f32x4_t{0.f, 0.f, 0.f, 0.f};
    }
    const uint4* wqf = (const uint4*)((const unsigned*)(wf + OWQT));
    const uint4* wkf = (const uint4*)((const unsigned*)(wf + OWKT));
#pragma unroll 2
    for (int ks8 = 0; ks8 < 8; ++ks8) {
      U4H8 bk_[2], bq_[2];
#pragma unroll
      for (int nt = 0; nt < 2; ++nt) {
        int col = nt * 16 + (lane & 15);
        int swz = (col & 7) << 4;
        bk_[nt].u = *(const uint4*)(xsb + ((col * 1024 + ks8 * 64 + ((lane >> 4) << 4)) ^ swz));
        bq_[nt].u = *(const uint4*)(xsb + ((col * 1024 + (8 + ks8) * 64 + ((lane >> 4) << 4)) ^ swz));
      }
      U4H8 aq, ak;
      aq.u = wqf[(wid * 8 + ks8) * 64 + lane];
      ak.u = wkf[(wid * 8 + ks8) * 64 + lane];
#pragma unroll
      for (int nt = 0; nt < 2; ++nt) {
        acck[nt] = mfma_16x16x32(ak.h, bk_[nt].h, acck[nt]);
        accq[nt] = mfma_16x16x32(aq.h, bq_[nt].h, accq[nt]);
      }
    }
    int ch0 = wid * 16 + ((lane >> 4) << 2);
    float4 bqv = *(const float4*)(wf + OBQ + ch0);
    float4 bkv = *(const float4*)(wf + OBK + ch0);
#pragma unroll
    for (int nt = 0; nt < 2; ++nt) {
      int col = nt * 16 + (lane & 15);
      *(float4*)(qout + ((size_t)b * N_ + n0 + col) * 64 + ch0) =
          make_float4(accq[nt][0] + bqv.x, accq[nt][1] + bqv.y,
                      accq[nt][2] + bqv.z, accq[nt][3] + bqv.w);
      *(float4*)(kout + ((size_t)b * N_ + n0 + col) * 64 + ch0) =
          make_float4(acck[nt][0] + bkv.x, acck[nt][1] + bkv.y,
                      acck[nt][2] + bkv.z, acck[nt][3] + bkv.w);
    }
  }
  __syncthreads();

  {
    f32x4_t acc2[4][2];
#pragma unroll
    for (int m = 0; m < 4; ++m)
#pragma unroll
      for (int nt = 0; nt < 2; ++nt) acc2[m][nt] = f32x4_t{0.f, 0.f, 0.f, 0.f};
    const uint4* w2f = (const uint4*)((const unsigned*)(wf + OW2P));
#pragma unroll 2
    for (int ks = 0; ks < 8; ++ks) {
      U4H8 bu[2];
#pragma unroll
      for (int nt = 0; nt < 2; ++nt) {
        int col = nt * 16 + (lane & 15);
        bu[nt].u = *(const uint4*)(hbb + ((col * 512 + ks * 64 + ((lane >> 4) << 4)) ^ ((col & 7) << 4)));
      }
#pragma unroll
      for (int m = 0; m < 4; ++m) {
        U4H8 a2;
        a2.u = w2f[((wid * 4 + m) * 8 + ks) * 64 + lane];
#pragma unroll
        for (int nt = 0; nt < 2; ++nt)
          acc2[m][nt] = mfma_16x16x32(a2.h, bu[nt].h, acc2[m][nt]);
      }
    }
#pragma unroll
    for (int m = 0; m < 4; ++m) {
      int ch0 = (wid * 4 + m) * 16 + ((lane >> 4) << 2);
      float4 bsv = *(const float4*)(wf + OBS2 + ch0);
#pragma unroll
      for (int nt = 0; nt < 2; ++nt) {
        int col = nt * 16 + (lane & 15);
        float v0 = acc2[m][nt][0] + accs[m][nt][0] + bsv.x;
        float v1 = acc2[m][nt][1] + accs[m][nt][1] + bsv.y;
        float v2 = acc2[m][nt][2] + accs[m][nt][2] + bsv.z;
        float v3 = acc2[m][nt][3] + accs[m][nt][3] + bsv.w;
        uint2 p;
        p.x = pkh2(v0, v1);
        p.y = pkh2(v2, v3);
        *(uint2*)(vbb + ((col * 512 + ch0 * 2) ^ ((col & 7) << 4))) = p;
      }
    }
  }
  __syncthreads();

  {
    f32x4_t accv[2], accr[2][2];
#pragma unroll
    for (int nt = 0; nt < 2; ++nt) {
      accv[nt] = f32x4_t{0.f, 0.f, 0.f, 0.f};
      accr[0][nt] = f32x4_t{0.f, 0.f, 0.f, 0.f};
      accr[1][nt] = f32x4_t{0.f, 0.f, 0.f, 0.f};
    }
    const uint4* wvf = (const uint4*)((const unsigned*)(wf + OWVP));
    const uint4* wrf = (const uint4*)((const unsigned*)(wf + OWRP));
#pragma unroll 2
    for (int ks = 0; ks < 8; ++ks) {
      U4H8 bu[2];
#pragma unroll
      for (int nt = 0; nt < 2; ++nt) {
        int col = nt * 16 + (lane & 15);
        bu[nt].u = *(const uint4*)(vbb + ((col * 512 + ks * 64 + ((lane >> 4) << 4)) ^ ((col & 7) << 4)));
      }
      U4H8 av;
      av.u = wvf[(wid * 8 + ks) * 64 + lane];
#pragma unroll
      for (int nt = 0; nt < 2; ++nt)
        accv[nt] = mfma_16x16x32(av.h, bu[nt].h, accv[nt]);
#pragma unroll
      for (int m2 = 0; m2 < 2; ++m2) {
        U4H8 ar;
        ar.u = wrf[((wid * 2 + m2) * 8 + ks) * 64 + lane];
#pragma unroll
        for (int nt = 0; nt < 2; ++nt)
          accr[m2][nt] = mfma_16x16x32(ar.h, bu[nt].h, accr[m2][nt]);
      }
    }
    {
      int ch0 = wid * 16 + ((lane >> 4) << 2);
      float4 bvv = *(const float4*)(wf + OBV + ch0);
#pragma unroll
      for (int nt = 0; nt < 2; ++nt) {
        int col = nt * 16 + (lane & 15);
        *(float4*)(vout + ((size_t)b * N_ + n0 + col) * 64 + ch0) =
            make_float4(accv[nt][0] + bvv.x, accv[nt][1] + bvv.y,
                        accv[nt][2] + bvv.z, accv[nt][3] + bvv.w);
      }
    }
#pragma unroll
    for (int m2 = 0; m2 < 2; ++m2) {
      int ch0 = (wid * 2 + m2) * 16 + ((lane >> 4) << 2);
      float4 brv = *(const float4*)(wf + OBR + ch0);
#pragma unroll
      for (int nt = 0; nt < 2; ++nt) {
        int col = nt * 16 + (lane & 15);
        *(float4*)(idenout + ((size_t)b * N_ + n0 + col) * 128 + ch0) =
            make_float4(accr[m2][nt][0] + brv.x, accr[m2][nt][1] + brv.y,
                        accr[m2][nt][2] + brv.z, accr[m2][nt][3] + brv.w);
      }
    }
  }
}

// ------------------------------------------------------------------
// u projection only (unchanged).
// ------------------------------------------------------------------
__global__ __launch_bounds__(256) void k_gemm_u(const float* __restrict__ wf,
                                                const float* __restrict__ x,
                                                float* __restrict__ out) {
  const int b = blockIdx.y;
  const int n0 = blockIdx.x * 64;
  const float* Wt = wf + OWUT;
  const float* bias = wf + OBU;
  __shared__ float ws_[16][64];
  __shared__ float xs_[16][64];
  const int tid = threadIdx.x, tm = tid & 15, tn = tid >> 4;
  float acc[4][4] = {};
  for (int kt = 0; kt < 256; kt += 16) {
    for (int i = tid; i < 1024; i += 256) {
      int kk = i >> 6, col = i & 63;
      ws_[kk][col] = Wt[(size_t)(kt + kk) * 64 + col];
      xs_[kk][col] = x[((size_t)b * 256 + kt + kk) * N_ + n0 + col];
    }
    __syncthreads();
#pragma unroll
    for (int kk = 0; kk < 16; ++kk) {
      float4 x4 = *(const float4*)&xs_[kk][tn * 4];
      float4 w4 = *(const float4*)&ws_[kk][tm * 4];
      float wv[4] = {w4.x, w4.y, w4.z, w4.w};
      float xv[4] = {x4.x, x4.y, x4.z, x4.w};
#pragma unroll
      for (int i = 0; i < 4; ++i)
#pragma unroll
        for (int j = 0; j < 4; ++j) acc[i][j] += wv[i] * xv[j];
    }
    __syncthreads();
  }
#pragma unroll
  for (int j = 0; j < 4; ++j) {
    *(float4*)(out + ((size_t)b * N_ + n0 + tn * 4 + j) * 64 + tm * 4) =
        make_float4(acc[0][j] + bias[tm * 4], acc[1][j] + bias[tm * 4 + 1],
                    acc[2][j] + bias[tm * 4 + 2], acc[3][j] + bias[tm * 4 + 3]);
  }
}

// ------------------------------------------------------------------
// Self-KNN v5 (unchanged): threshold + bitonic sort, exact.
// ------------------------------------------------------------------
__device__ __forceinline__ unsigned long long bitonic64_(unsigned long long v,
                                                         int lane) {
#pragma unroll
  for (int k = 2; k <= 64; k <<= 1) {
#pragma unroll
    for (int j = k >> 1; j > 0; j >>= 1) {
      unsigned long long o = (unsigned long long)__shfl_xor((long long)v, j);
      bool up = (lane & k) == 0;
      bool lower = (lane & j) == 0;
      bool keepmin = (lower == up);
      unsigned long long mn = o < v ? o : v;
      unsigned long long mx = o < v ? v : o;
      v = keepmin ? mn : mx;
    }
  }
  return v;
}

__global__ __launch_bounds__(256, 8) void k_knn(const float* __restrict__ pos,
                                                int* __restrict__ idxout) {
  const int b = blockIdx.x >> 11, n = blockIdx.x & 2047;
  __shared__ unsigned long long wkeys[4][20];
  __shared__ unsigned long long cand[4][64];
  const int tid = threadIdx.x;
  const int lane = tid & 63, wv = tid >> 6;
  const float* pb = pos + (size_t)b * 3 * N_;
  const double xq = pb[n], yq = pb[N_ + n], zq = pb[2 * N_ + n];
  const double sq = xq * xq + yq * yq + zq * zq;
  unsigned long long key[8];
#pragma unroll
  for (int s = 0; s < 8; ++s) {
    int i = tid + s * 256;
    double x = pb[i], y = pb[N_ + i], z = pb[2 * N_ + i];
    double psq = x * x + y * y + z * z;
    double dot = xq * x + yq * y + zq * z;
    double d2 = fmax((sq + psq) - 2.0 * dot, 0.0);
    key[s] = ((unsigned long long)__double_as_longlong(d2) & ~0x7FFull) |
             (unsigned long long)i;
  }
  unsigned long long m = key[0];
#pragma unroll
  for (int s = 1; s < 8; ++s) m = key[s] < m ? key[s] : m;

  unsigned long long v = bitonic64_(m, lane);
  unsigned long long T = (unsigned long long)__shfl((long long)v, 19);

  int c = 0;
#pragma unroll
  for (int s = 0; s < 8; ++s) c += (key[s] <= T) ? 1 : 0;
  int inc = c;
#pragma unroll
  for (int d = 1; d < 64; d <<= 1) {
    int t = __shfl_up(inc, d);
    if (lane >= d) inc += t;
  }
  const int C = __shfl(inc, 63);
  const int off = inc - c;

  if (C <= 64) {
    int o2 = off;
#pragma unroll
    for (int s = 0; s < 8; ++s) {
      if (key[s] <= T) { cand[wv][o2] = key[s]; ++o2; }
    }
    __builtin_amdgcn_wave_barrier();
    asm volatile("s_waitcnt lgkmcnt(0)" ::: "memory");
    unsigned long long cv = (lane < C) ? cand[wv][lane] : ~0ull;
    cv = bitonic64_(cv, lane);
    if (lane < K_) wkeys[wv][lane] = cv;
  } else {
    for (int r = 0; r < K_; ++r) {
      unsigned long long bk = key[0];
#pragma unroll
      for (int s = 1; s < 8; ++s) bk = key[s] < bk ? key[s] : bk;
      unsigned long long wk = bk;
#pragma unroll
      for (int mm = 32; mm; mm >>= 1) {
        unsigned long long ok = (unsigned long long)__shfl_xor((long long)wk, mm);
        if (ok < wk) wk = ok;
      }
      if (lane == 0) wkeys[wv][r] = wk;
      const int widx = (int)(wk & 0x7FF);
#pragma unroll
      for (int s = 0; s < 8; ++s)
        if (widx == tid + s * 256) key[s] = ~0ull;
    }
  }
  __syncthreads();

  if (tid < 128) {
    const int w = tid >> 5, p = tid & 31;
    if (p < 20) {
      const unsigned long long Kk = wkeys[w][p];
      int rank = p;
#pragma unroll
      for (int w2 = 0; w2 < 4; ++w2) {
        if (w2 == w) continue;
        int lo = 0, hi = 20;
        while (lo < hi) {
          int mid = (lo + hi) >> 1;
          if (wkeys[w2][mid] < Kk) lo = mid + 1; else hi = mid;
        }
        rank += lo;
      }
      if (rank < K_)
        idxout[((size_t)b * N_ + n) * K_ + rank] = (int)(Kk & 0x7FF);
    }
  }
}

// ------------------------------------------------------------------
// Fused attention tail v7: QB=2 + LDS diet for 6 blocks/CU.
//  - P1 writes linear bases (q-k+u_rel), (v+u_rel) to LDS f16
//    (sb0/vb0); sreg/vreg register arrays gone.
//  - P3 MFMA epilogue folds pe directly: S = sb0+pe, sVal = vb0+pe
//    (in-place RMW, bijective per element). pe buffer + P3b deleted.
//  - P4/P5 chunked over 2x128 channels: h buffer 24.6KB -> 12.3KB;
//    P5 accumulators persist across chunks.
// LDS 26784 B -> 6 blocks/CU. Map (bytes):
//   S@0 (6144) | region@6144..18432: t1@6144, sb0@12288(5120),
//   h-chunk@6144(12288) | misc@18432..19072 (dead after P2) |
//   lg f32[40][129]@0 (20640; overlays S+region+misc, all dead) |
//   sVal(vb0)@20640 (5120) | aggs@25760 (1024) -> 26784.
// ------------------------------------------------------------------
__global__ __launch_bounds__(256, 6) void k_attn(
    const float* __restrict__ wf,
    const float* __restrict__ qb, const float* __restrict__ kb,
    const float* __restrict__ vb, const float* __restrict__ ub,
    const float* __restrict__ idenb, const int* __restrict__ idxb,
    const float* __restrict__ pos, float* __restrict__ out) {
  const int lb = ((int)blockIdx.x & 7) * 1024 + ((int)blockIdx.x >> 3);
  const int b = lb >> 10, n0 = (lb & 1023) * 2;
  const int tid = threadIdx.x;
  const int lane = tid & 63, wid = tid >> 6;

  __shared__ __align__(16) char smem[26784];
  char*  Sb   = smem;
  char*  t1b  = smem + 6144;
  char*  sb0  = smem + 12288;
  char*  hb   = smem + 6144;
  int*   idxs = (int*)(smem + 18432);
  float* prx  = (float*)(smem + 18592);
  float* pry  = (float*)(smem + 18752);
  float* prz  = (float*)(smem + 18912);
  float* lg   = (float*)smem;
  char*  svb  = smem + 20640;
  float* aggs = (float*)(smem + 25760);

  if (tid < 40) {
    int qi = tid >= 20;
    idxs[tid] = idxb[((size_t)b * N_ + n0 + qi) * K_ + (tid - qi * 20)] & 2047;
  }
  __syncthreads();

  // P1: gathers -> sb0/vb0 f16 (swz). Wave w owns cols w*10..w*10+9.
  {
    const int qi = wid >> 1;
    size_t rowq = ((size_t)b * N_ + n0 + qi) * 64;
    float qvo = qb[rowq + lane];
    float ufo = ub[rowq + lane];
#pragma unroll
    for (int t = 0; t < 10; ++t) {
      int col = wid * 10 + t;
      int j = idxs[col];
      size_t rowj = ((size_t)b * N_ + j) * 64;
      float kvv = kb[rowj + lane], vvv = vb[rowj + lane], uvv = ub[rowj + lane];
      float ur = ufo - uvv;
      int ro = (col * 128 + lane * 2) ^ ((col & 7) << 4);
      *(_Float16*)(sb0 + ro) = (_Float16)((qvo - kvv) + ur);
      *(_Float16*)(svb + ro) = (_Float16)(vvv + ur);
    }
    if (tid < 40) {
      int j = idxs[tid];
      int qn = n0 + (tid >= 20);
      const float* pp = pos + (size_t)b * 3 * N_;
      prx[tid] = pp[qn] - pp[j];
      pry[tid] = pp[N_ + qn] - pp[N_ + j];
      prz[tid] = pp[2 * N_ + qn] - pp[2 * N_ + j];
    }
  }
  __syncthreads();

  // P2: pos-MLP layer1 + BN + relu -> t1 f16 [col][ph] swz
  {
    int ph = lane;
    float w0 = wf[OPW1 + ph * 3], w1 = wf[OPW1 + ph * 3 + 1], w2 = wf[OPW1 + ph * 3 + 2];
    float pb1 = wf[OPB1 + ph], sc = wf[OPSC + ph], sh = wf[OPSH + ph];
#pragma unroll
    for (int t = 0; t < 10; ++t) {
      int col = wid * 10 + t;
      float u = pb1 + w0 * prx[col] + w1 * pry[col] + w2 * prz[col];
      float tv = fmaxf(u * sc + sh, 0.f);
      *(_Float16*)(t1b + ((col * 128 + ph * 2) ^ ((col & 7) << 4))) = (_Float16)tv;
    }
  }
  __syncthreads();

  // P3: pe = pm_w2 @ t1 via MFMA; epilogue folds into S and sVal
  {
    f32x4_t pacc[3];
#pragma unroll
    for (int nt = 0; nt < 3; ++nt) pacc[nt] = f32x4_t{0.f, 0.f, 0.f, 0.f};
    const int mt = wid;
#pragma unroll
    for (int ks = 0; ks < 2; ++ks) {
      U4H8 a;
      a.u = ((const uint4*)((const unsigned*)(wf + OPWF)))[(mt * 2 + ks) * 64 + lane];
#pragma unroll
      for (int nt = 0; nt < 3; ++nt) {
        int kc = nt * 16 + (lane & 15);
        U4H8 bu;
        bu.u = *(const uint4*)(t1b + ((kc * 128 + (ks * 32 + ((lane >> 4) << 3)) * 2) ^ ((kc & 7) << 4)));
        pacc[nt] = mfma_16x16x32(a.h, bu.h, pacc[nt]);
      }
    }
    const int o0 = mt * 16 + ((lane >> 4) << 2);
    float4 pb2v = *(const float4*)(wf + OPB2 + o0);
#pragma unroll
    for (int nt = 0; nt < 3; ++nt) {
      int kc = nt * 16 + (lane & 15);
      if (kc < 40) {
        int ro = (kc * 128 + o0 * 2) ^ ((kc & 7) << 4);
        float pe0 = pacc[nt][0] + pb2v.x, pe1 = pacc[nt][1] + pb2v.y;
        float pe2 = pacc[nt][2] + pb2v.z, pe3 = pacc[nt][3] + pb2v.w;
        const _Float16* sp = (const _Float16*)(sb0 + ro);
        _Float16* vp = (_Float16*)(svb + ro);
        uint2 ps, pv;
        ps.x = pkh2((float)sp[0] + pe0, (float)sp[1] + pe1);
        ps.y = pkh2((float)sp[2] + pe2, (float)sp[3] + pe3);
        pv.x = pkh2((float)vp[0] + pe0, (float)vp[1] + pe1);
        pv.y = pkh2((float)vp[2] + pe2, (float)vp[3] + pe3);
        *(uint2*)(Sb + ro) = ps;
        *(uint2*)vp = pv;
      }
    }
  }
  __syncthreads();

  // P4/P5 chunked: chunk c covers channels c*128..c*128+127
  f32x4_t acc5[2][3];
#pragma unroll
  for (int m = 0; m < 2; ++m)
#pragma unroll
    for (int nt = 0; nt < 3; ++nt) acc5[m][nt] = f32x4_t{0.f, 0.f, 0.f, 0.f};
#pragma unroll
  for (int c = 0; c < 2; ++c) {
    // P4 chunk: h = relu(bn(am_w1 @ S)), mt = c*8 + wid*2 + m
    {
      f32x4_t acc[2][3];
#pragma unroll
      for (int m = 0; m < 2; ++m)
#pragma unroll
        for (int nt = 0; nt < 3; ++nt) acc[m][nt] = f32x4_t{0.f, 0.f, 0.f, 0.f};
#pragma unroll
      for (int ks = 0; ks < 2; ++ks) {
        U4H8 bfr[3];
#pragma unroll
        for (int nt = 0; nt < 3; ++nt) {
          int kc = nt * 16 + (lane & 15);
          bfr[nt].u = *(const uint4*)(Sb + ((kc * 128 + (ks * 32 + ((lane >> 4) << 3)) * 2) ^ ((kc & 7) << 4)));
        }
#pragma unroll
        for (int m = 0; m < 2; ++m) {
          U4H8 a;
          a.u = ((const uint4*)((const unsigned*)(wf + OAWF)))[((c * 8 + wid * 2 + m) * 2 + ks) * 64 + lane];
#pragma unroll
          for (int nt = 0; nt < 3; ++nt)
            acc[m][nt] = mfma_16x16x32(a.h, bfr[nt].h, acc[m][nt]);
        }
      }
#pragma unroll
      for (int m = 0; m < 2; ++m) {
        const int cg = (c * 8 + wid * 2 + m) * 16 + ((lane >> 4) << 2);  // global ch
        const int cl = (wid * 2 + m) * 16 + ((lane >> 4) << 2);          // chunk-local
        float4 ab1 = *(const float4*)(wf + OAB1 + cg);
        float4 asc = *(const float4*)(wf + OASC + cg);
        float4 ash = *(const float4*)(wf + OASH + cg);
#pragma unroll
        for (int nt = 0; nt < 3; ++nt) {
          int kc = nt * 16 + (lane & 15);
          float h0 = fmaxf((acc[m][nt][0] + ab1.x) * asc.x + ash.x, 0.f);
          float h1 = fmaxf((acc[m][nt][1] + ab1.y) * asc.y + ash.y, 0.f);
          float h2 = fmaxf((acc[m][nt][2] + ab1.z) * asc.z + ash.z, 0.f);
          float h3 = fmaxf((acc[m][nt][3] + ab1.w) * asc.w + ash.w, 0.f);
          uint2 p;
          p.x = pkh2(h0, h1);
          p.y = pkh2(h2, h3);
          *(uint2*)(hb + ((kc * 256 + cl * 2) ^ ((kc & 7) << 4))) = p;
        }
      }
    }
    __syncthreads();
    // P5 chunk: accumulate lg += wt_chunk @ h_chunk (4 local ks)
    {
#pragma unroll
      for (int ksl = 0; ksl < 4; ++ksl) {
        U4H8 bfr[3];
#pragma unroll
        for (int nt = 0; nt < 3; ++nt) {
          int kc = nt * 16 + (lane & 15);
          bfr[nt].u = *(const uint4*)(hb + ((kc * 256 + (ksl * 32 + ((lane >> 4) << 3)) * 2) ^ ((kc & 7) << 4)));
        }
#pragma unroll
        for (int m = 0; m < 2; ++m) {
          U4H8 a;
          a.u = ((const uint4*)((const unsigned*)(wf + OWTF)))[((wid * 2 + m) * 8 + (c * 4 + ksl)) * 64 + lane];
#pragma unroll
          for (int nt = 0; nt < 3; ++nt)
            acc5[m][nt] = mfma_16x16x32(a.h, bfr[nt].h, acc5[m][nt]);
        }
      }
    }
    __syncthreads();
  }

  // lg write (S/h/misc all dead; lg overlays them)
#pragma unroll
  for (int m = 0; m < 2; ++m) {
    const int or0 = (wid * 2 + m) * 16 + ((lane >> 4) << 2);
#pragma unroll
    for (int nt = 0; nt < 3; ++nt) {
      int kc = nt * 16 + (lane & 15);
      if (kc < 40) {
#pragma unroll
        for (int r = 0; r < 4; ++r) lg[kc * 129 + or0 + r] = acc5[m][nt][r];
      }
    }
  }
  __syncthreads();

  // P6: softmax over k + aggregate; all 256 threads (qsel = tid>>7)
  {
    const int qsel = tid >> 7, orr = tid & 127, o = orr >> 1;
    float l[20];
#pragma unroll
    for (int kk = 0; kk < 20; ++kk) l[kk] = lg[(qsel * 20 + kk) * 129 + orr];
    float bt = wf[OABT + o];
    float m = -3.4e38f;
#pragma unroll
    for (int kk = 0; kk < 20; ++kk) { l[kk] += bt; m = fmaxf(m, l[kk]); }
    float s = 0.f;
#pragma unroll
    for (int kk = 0; kk < 20; ++kk) { l[kk] = expf(l[kk] - m); s += l[kk]; }
    float inv = 1.f / s;
    float a = 0.f;
#pragma unroll
    for (int kk = 0; kk < 20; ++kk) {
      int row = qsel * 20 + kk;
      a += l[kk] * (float)(*(const _Float16*)(svb + ((row * 128 + o * 2) ^ ((row & 7) << 4))));
    }
    aggs[qsel * 128 + orr] = a * inv;
  }
  __syncthreads();

  // P7: y = we @ agg + be + iden; native we [co][o], float4
  {
    const int co = tid & 127, r = tid >> 7;
    float y0 = wf[OBE + co], y1 = y0;
    const float* w = wf + OWET + co * 64;
#pragma unroll 4
    for (int o4 = 0; o4 < 16; ++o4) {
      float4 w4 = *(const float4*)(w + o4 * 4);
      const float wv[4] = {w4.x, w4.y, w4.z, w4.w};
#pragma unroll
      for (int j = 0; j < 4; ++j) {
        int oi = o4 * 4 + j;
        y0 += wv[j] * aggs[oi * 2 + r];
        y1 += wv[j] * aggs[128 + oi * 2 + r];
      }
    }
    float id0 = idenb[((size_t)b * N_ + n0) * 128 + co];
    float id1 = idenb[((size_t)b * N_ + n0 + 1) * 128 + co];
    size_t obase = ((size_t)b * 128 + co) * (size_t)(2 * N_);
    out[obase + 2 * n0 + r] = y0 + id0;
    out[obase + 2 * n0 + 2 + r] = y1 + id1;
  }
}

extern "C" void kernel_launch(void* const* d_in, const int* in_sizes, int n_in,
                              void* d_out, int out_size, void* d_ws, size_t ws_size,
                              hipStream_t stream) {
  (void)in_sizes; (void)n_in; (void)out_size; (void)ws_size;
  InPtrs ip;
  for (int i = 0; i < 38; ++i) ip.p[i] = (const float*)d_in[i];
  char* ws = (char*)d_ws;
  float* wf    = (float*)(ws + OFFB_WF);
  int*   idxb  = (int*)(ws + OFFB_IDX);
  float* qb    = (float*)(ws + OFFB_Q);
  float* kb    = (float*)(ws + OFFB_K);
  float* ubuf  = (float*)(ws + OFFB_U);
  float* vbuf  = (float*)(ws + OFFB_V);
  float* idenb = (float*)(ws + OFFB_IDEN);

  k_prep<<<dim3(256), dim3(256), 0, stream>>>(ip, wf);
  k_mv<<<dim3(64, 8), dim3(256), 0, stream>>>(wf, ip.p[1], ip.p[2], vbuf, idenb, qb, kb);
  k_gemm_u<<<dim3(32, 8), dim3(256), 0, stream>>>(wf, ip.p[3], ubuf);
  k_knn<<<dim3(B_ * N_), dim3(256), 0, stream>>>(ip.p[0], idxb);
  k_attn<<<dim3(B_ * N_ / 2), dim3(256), 0, stream>>>(wf, qb, kb, vbuf, ubuf, idenb, idxb,
                                                      ip.p[0], (float*)d_out);
}

// Round 13
// 451.078 us; speedup vs baseline: 1.0878x; 1.0878x over previous
//
#include <hip/hip_runtime.h>
#include <hip/hip_bf16.h>

constexpr int B_ = 8, N_ = 2048, K_ = 20;
constexpr float EPS_ = 1e-5f;

// ---- weight area offsets (float slots; "u" = uint32 of packed half2) ----
// mv/q/k matrices stored as MFMA A-fragments (16x16x32 f16):
// frag index ((mt*KS+ks)*64+l)*4+q -> m = mt*16+(l&15), k = ks*32+(l>>4)*8+2q
constexpr int OW1P = 0;                    // u W1 frags  mt16 ks16 = 65536u
constexpr int OWSP = OW1P + 256 * 256;     // u Ws frags  65536u
constexpr int OW2P = OWSP + 256 * 256;     // u W2 frags  mt16 ks8 = 32768u
constexpr int OWVP = OW2P + 128 * 256;     // u wv frags  mt4 ks8 = 8192u
constexpr int OWRP = OWVP + 128 * 64;      // u wr frags  mt8 ks8 = 16384u
constexpr int OWQT = OWRP + 128 * 128;     // u wq frags  mt4 ks8 = 8192u
constexpr int OWKT = OWQT + 256 * 64;      // u wk frags  8192u
constexpr int OWUT = OWKT + 256 * 64;      // f32 wu^T [256][64]
constexpr int OWET = OWUT + 256 * 64;      // f32 we NATIVE [co 128][o 64]
constexpr int OWTF = OWET + 64 * 128;      // u  wt A-frags  [mt8][ks8][l64]x4u
constexpr int OAWF = OWTF + 16384;         // u  am_w1 A-frags [mt16][ks2][l64]x4u
constexpr int OPWF = OAWF + 8192;          // u  pm_w2 A-frags [mt4][ks2][l64]x4u
constexpr int OPW1 = OPWF + 2048;          // pm_w1 [ph][3]
constexpr int OB1  = OPW1 + 192;           // mv_b1 [256]
constexpr int OBS2 = OB1 + 256;            // mv_bs + mv_b2 [256]
constexpr int OBQ  = OBS2 + 256;
constexpr int OBK  = OBQ + 64;
constexpr int OBV  = OBK + 64;
constexpr int OBU  = OBV + 64;
constexpr int OBR  = OBU + 64;             // [128]
constexpr int OBE  = OBR + 128;            // [128]
constexpr int OPB1 = OBE + 128;            // [64]
constexpr int OPSC = OPB1 + 64;
constexpr int OPSH = OPSC + 64;
constexpr int OPB2 = OPSH + 64;
constexpr int OASC = OPB2 + 64;            // [256]
constexpr int OASH = OASC + 256;
constexpr int OAB1 = OASH + 256;
constexpr int OABT = OAB1 + 256;           // [64]

// ---- workspace byte offsets (28 MiB total) ----
constexpr size_t OFFB_WF   = 0;
constexpr size_t OFFB_IDX  = (size_t)2 << 20;
constexpr size_t OFFB_Q    = (size_t)4 << 20;   // [b][n][64]
constexpr size_t OFFB_K    = (size_t)8 << 20;   // [b][n][64]
constexpr size_t OFFB_U    = (size_t)12 << 20;  // [b][n][64]
constexpr size_t OFFB_V    = (size_t)16 << 20;  // [b][n][64]
constexpr size_t OFFB_IDEN = (size_t)20 << 20;  // [b][n][128]

struct InPtrs { const float* p[38]; };

// ---- f16 helpers ----
typedef _Float16 half2_t __attribute__((ext_vector_type(2)));
typedef _Float16 f16x8_t __attribute__((ext_vector_type(8)));
typedef float    f32x4_t __attribute__((ext_vector_type(4)));

union U4H8 { uint4 u; f16x8_t h; };

__device__ __forceinline__ unsigned pkh2(float a, float b) {
  union { unsigned u; half2_t h; } x;
  x.h = half2_t{(_Float16)a, (_Float16)b};
  return x.u;
}
__device__ __forceinline__ f32x4_t mfma_16x16x32(f16x8_t a, f16x8_t b, f32x4_t c) {
  return __builtin_amdgcn_mfma_f32_16x16x32_f16(a, b, c, 0, 0, 0);
}

// ------------------------------------------------------------------
// Weight prep (unchanged).
// ------------------------------------------------------------------
__global__ __launch_bounds__(256) void k_prep(InPtrs in, float* __restrict__ wf) {
  const int tid = blockIdx.x * 256 + threadIdx.x;
  const int nth = gridDim.x * 256;
  const float *mv_w1 = in.p[4], *mv_b1 = in.p[5], *mv_w2 = in.p[6], *mv_b2 = in.p[7],
              *mv_ws = in.p[8], *mv_bs = in.p[9], *wk = in.p[10], *bk = in.p[11],
              *wq = in.p[12], *bq = in.p[13], *wv = in.p[14], *bv = in.p[15],
              *wu = in.p[16], *bu = in.p[17], *pm_w1 = in.p[18], *pm_b1 = in.p[19],
              *pm_g = in.p[20], *pm_be = in.p[21], *pm_m = in.p[22], *pm_v = in.p[23],
              *pm_w2 = in.p[24], *pm_b2 = in.p[25], *am_w1 = in.p[26], *am_b1 = in.p[27],
              *am_g = in.p[28], *am_be = in.p[29], *am_m = in.p[30], *am_v = in.p[31],
              *am_wt = in.p[32], *am_bt = in.p[33], *we = in.p[34], *be = in.p[35],
              *wr = in.p[36], *br = in.p[37];

  {
    unsigned* w1f = (unsigned*)(wf + OW1P);
    for (int i = tid; i < 65536; i += nth) {
      int q = i & 3, l = (i >> 2) & 63, ks = (i >> 8) & 15, mt = i >> 12;
      int m = mt * 16 + (l & 15);
      int k = ks * 32 + ((l >> 4) << 3) + 2 * q;
      w1f[i] = pkh2(mv_w1[m * 512 + k], mv_w1[m * 512 + k + 1]);
    }
    unsigned* wsf = (unsigned*)(wf + OWSP);
    for (int i = tid; i < 65536; i += nth) {
      int q = i & 3, l = (i >> 2) & 63, ks = (i >> 8) & 15, mt = i >> 12;
      int m = mt * 16 + (l & 15);
      int k = ks * 32 + ((l >> 4) << 3) + 2 * q;
      wsf[i] = pkh2(mv_ws[m * 512 + k], mv_ws[m * 512 + k + 1]);
    }
    unsigned* w2f = (unsigned*)(wf + OW2P);
    for (int i = tid; i < 32768; i += nth) {
      int q = i & 3, l = (i >> 2) & 63, ks = (i >> 8) & 7, mt = i >> 11;
      int m = mt * 16 + (l & 15);
      int k = ks * 32 + ((l >> 4) << 3) + 2 * q;
      w2f[i] = pkh2(mv_w2[m * 256 + k], mv_w2[m * 256 + k + 1]);
    }
    unsigned* wvf = (unsigned*)(wf + OWVP);
    for (int i = tid; i < 8192; i += nth) {
      int q = i & 3, l = (i >> 2) & 63, ks = (i >> 8) & 7, mt = i >> 11;
      int m = mt * 16 + (l & 15);
      int k = ks * 32 + ((l >> 4) << 3) + 2 * q;
      wvf[i] = pkh2(wv[m * 256 + k], wv[m * 256 + k + 1]);
    }
    unsigned* wrf = (unsigned*)(wf + OWRP);
    for (int i = tid; i < 16384; i += nth) {
      int q = i & 3, l = (i >> 2) & 63, ks = (i >> 8) & 7, mt = i >> 11;
      int m = mt * 16 + (l & 15);
      int k = ks * 32 + ((l >> 4) << 3) + 2 * q;
      wrf[i] = pkh2(wr[m * 256 + k], wr[m * 256 + k + 1]);
    }
    unsigned* wqf = (unsigned*)(wf + OWQT);
    for (int i = tid; i < 8192; i += nth) {
      int q = i & 3, l = (i >> 2) & 63, ks = (i >> 8) & 7, mt = i >> 11;
      int m = mt * 16 + (l & 15);
      int k = ks * 32 + ((l >> 4) << 3) + 2 * q;
      wqf[i] = pkh2(wq[m * 256 + k], wq[m * 256 + k + 1]);
    }
    unsigned* wkf = (unsigned*)(wf + OWKT);
    for (int i = tid; i < 8192; i += nth) {
      int q = i & 3, l = (i >> 2) & 63, ks = (i >> 8) & 7, mt = i >> 11;
      int m = mt * 16 + (l & 15);
      int k = ks * 32 + ((l >> 4) << 3) + 2 * q;
      wkf[i] = pkh2(wk[m * 256 + k], wk[m * 256 + k + 1]);
    }
  }
  for (int i = tid; i < 256 * 64; i += nth) { int c = i >> 6, m = i & 63; wf[OWUT + i] = wu[m * 256 + c]; }
  for (int i = tid; i < 64 * 128; i += nth) wf[OWET + i] = we[i];  // native [co][o]

  {
    unsigned* wtf = (unsigned*)(wf + OWTF);
    for (int i = tid; i < 16384; i += nth) {
      int q = i & 3, l = (i >> 2) & 63, ks = (i >> 8) & 7, mt = i >> 11;
      int orr = mt * 16 + (l & 15);
      int c = ks * 32 + ((l >> 4) << 3) + 2 * q;
      wtf[i] = pkh2(am_wt[c * 128 + orr], am_wt[(c + 1) * 128 + orr]);
    }
  }
  {
    unsigned* awf = (unsigned*)(wf + OAWF);
    for (int i = tid; i < 8192; i += nth) {
      int q = i & 3, l = (i >> 2) & 63, ks = (i >> 8) & 1, mt = i >> 9;
      int c = mt * 16 + (l & 15);
      int o = ks * 32 + ((l >> 4) << 3) + 2 * q;
      awf[i] = pkh2(am_w1[c * 64 + o], am_w1[c * 64 + o + 1]);
    }
  }
  {
    unsigned* pwf = (unsigned*)(wf + OPWF);
    for (int i = tid; i < 2048; i += nth) {
      int q = i & 3, l = (i >> 2) & 63, ks = (i >> 8) & 1, mt = i >> 9;
      int o = mt * 16 + (l & 15);
      int ph = ks * 32 + ((l >> 4) << 3) + 2 * q;
      pwf[i] = pkh2(pm_w2[o * 64 + ph], pm_w2[o * 64 + ph + 1]);
    }
  }
  for (int i = tid; i < 192; i += nth) wf[OPW1 + i] = pm_w1[i];
  for (int i = tid; i < 256; i += nth) {
    wf[OB1 + i] = mv_b1[i];
    wf[OBS2 + i] = mv_bs[i] + mv_b2[i];
    float sc = am_g[i] / sqrtf(am_v[i] + EPS_);
    wf[OASC + i] = sc;
    wf[OASH + i] = am_be[i] - am_m[i] * sc;
    wf[OAB1 + i] = am_b1[i];
  }
  for (int i = tid; i < 64; i += nth) {
    wf[OBQ + i] = bq[i]; wf[OBK + i] = bk[i];
    wf[OBV + i] = bv[i]; wf[OBU + i] = bu[i];
    wf[OABT + i] = am_bt[i]; wf[OPB1 + i] = pm_b1[i]; wf[OPB2 + i] = pm_b2[i];
    float sc = pm_g[i] / sqrtf(pm_v[i] + EPS_);
    wf[OPSC + i] = sc;
    wf[OPSH + i] = pm_be[i] - pm_m[i] * sc;
  }
  for (int i = tid; i < 128; i += nth) { wf[OBR + i] = br[i]; wf[OBE + i] = be[i]; }
}

// ------------------------------------------------------------------
// Fused mv-MLP v3 (unchanged): all 5 mv GEMMs + q/k on MFMA.
// ------------------------------------------------------------------
__global__ __launch_bounds__(256, 2) void k_mv(const float* __restrict__ wf,
                                               const float* __restrict__ keyf,
                                               const float* __restrict__ qryf,
                                               float* __restrict__ vout,
                                               float* __restrict__ idenout,
                                               float* __restrict__ qout,
                                               float* __restrict__ kout) {
  const int b = blockIdx.y;
  const int n0 = blockIdx.x * 32;
  const int tid = threadIdx.x, lane = tid & 63, wid = tid >> 6;
  __shared__ __align__(16) char smem[49152];
  char* xsb = smem;
  char* hbb = smem + 32768;
  char* vbb = smem;

  {
    const int col = tid & 31, kq = tid >> 5;
    const int swz = (col & 7) << 4;
#pragma unroll 4
    for (int it = 0; it < 32; ++it) {
      int k2 = it * 8 + kq;
      int c = 2 * k2;
      const float* s = (c < 256) ? keyf : qryf;
      size_t base = ((size_t)b * 256 + (c & 255)) * N_ + n0 + col;
      float x0 = s[base], x1 = s[base + N_];
      *(unsigned*)(xsb + ((col * 1024 + k2 * 4) ^ swz)) = pkh2(x0, x1);
    }
  }
  __syncthreads();

  f32x4_t acch[4][2], accs[4][2];
#pragma unroll
  for (int m = 0; m < 4; ++m)
#pragma unroll
    for (int nt = 0; nt < 2; ++nt) {
      acch[m][nt] = f32x4_t{0.f, 0.f, 0.f, 0.f};
      accs[m][nt] = f32x4_t{0.f, 0.f, 0.f, 0.f};
    }
  {
    const uint4* w1f = (const uint4*)((const unsigned*)(wf + OW1P));
    const uint4* wsf = (const uint4*)((const unsigned*)(wf + OWSP));
#pragma unroll 2
    for (int ks = 0; ks < 16; ++ks) {
      U4H8 bu[2];
#pragma unroll
      for (int nt = 0; nt < 2; ++nt) {
        int col = nt * 16 + (lane & 15);
        bu[nt].u = *(const uint4*)(xsb + ((col * 1024 + ks * 64 + ((lane >> 4) << 4)) ^ ((col & 7) << 4)));
      }
#pragma unroll
      for (int m = 0; m < 4; ++m) {
        U4H8 a1, as_;
        a1.u = w1f[((wid * 4 + m) * 16 + ks) * 64 + lane];
        as_.u = wsf[((wid * 4 + m) * 16 + ks) * 64 + lane];
#pragma unroll
        for (int nt = 0; nt < 2; ++nt) {
          acch[m][nt] = mfma_16x16x32(a1.h, bu[nt].h, acch[m][nt]);
          accs[m][nt] = mfma_16x16x32(as_.h, bu[nt].h, accs[m][nt]);
        }
      }
    }
  }
#pragma unroll
  for (int m = 0; m < 4; ++m) {
    int ch0 = (wid * 4 + m) * 16 + ((lane >> 4) << 2);
    float4 b1v = *(const float4*)(wf + OB1 + ch0);
#pragma unroll
    for (int nt = 0; nt < 2; ++nt) {
      int col = nt * 16 + (lane & 15);
      float h0 = fmaxf(acch[m][nt][0] + b1v.x, 0.f);
      float h1 = fmaxf(acch[m][nt][1] + b1v.y, 0.f);
      float h2 = fmaxf(acch[m][nt][2] + b1v.z, 0.f);
      float h3 = fmaxf(acch[m][nt][3] + b1v.w, 0.f);
      uint2 p;
      p.x = pkh2(h0, h1);
      p.y = pkh2(h2, h3);
      *(uint2*)(hbb + ((col * 512 + ch0 * 2) ^ ((col & 7) << 4))) = p;
    }
  }

  {
    f32x4_t accq[2], acck[2];
#pragma unroll
    for (int nt = 0; nt < 2; ++nt) {
      accq[nt] = f32x4_t{0.f, 0.f, 0.f, 0.f};
      acck[nt] = f32x4_t{0.f, 0.f, 0.f, 0.f};
    }
    const uint4* wqf = (const uint4*)((const unsigned*)(wf + OWQT));
    const uint4* wkf = (const uint4*)((const unsigned*)(wf + OWKT));
#pragma unroll 2
    for (int ks8 = 0; ks8 < 8; ++ks8) {
      U4H8 bk_[2], bq_[2];
#pragma unroll
      for (int nt = 0; nt < 2; ++nt) {
        int col = nt * 16 + (lane & 15);
        int swz = (col & 7) << 4;
        bk_[nt].u = *(const uint4*)(xsb + ((col * 1024 + ks8 * 64 + ((lane >> 4) << 4)) ^ swz));
        bq_[nt].u = *(const uint4*)(xsb + ((col * 1024 + (8 + ks8) * 64 + ((lane >> 4) << 4)) ^ swz));
      }
      U4H8 aq, ak;
      aq.u = wqf[(wid * 8 + ks8) * 64 + lane];
      ak.u = wkf[(wid * 8 + ks8) * 64 + lane];
#pragma unroll
      for (int nt = 0; nt < 2; ++nt) {
        acck[nt] = mfma_16x16x32(ak.h, bk_[nt].h, acck[nt]);
        accq[nt] = mfma_16x16x32(aq.h, bq_[nt].h, accq[nt]);
      }
    }
    int ch0 = wid * 16 + ((lane >> 4) << 2);
    float4 bqv = *(const float4*)(wf + OBQ + ch0);
    float4 bkv = *(const float4*)(wf + OBK + ch0);
#pragma unroll
    for (int nt = 0; nt < 2; ++nt) {
      int col = nt * 16 + (lane & 15);
      *(float4*)(qout + ((size_t)b * N_ + n0 + col) * 64 + ch0) =
          make_float4(accq[nt][0] + bqv.x, accq[nt][1] + bqv.y,
                      accq[nt][2] + bqv.z, accq[nt][3] + bqv.w);
      *(float4*)(kout + ((size_t)b * N_ + n0 + col) * 64 + ch0) =
          make_float4(acck[nt][0] + bkv.x, acck[nt][1] + bkv.y,
                      acck[nt][2] + bkv.z, acck[nt][3] + bkv.w);
    }
  }
  __syncthreads();

  {
    f32x4_t acc2[4][2];
#pragma unroll
    for (int m = 0; m < 4; ++m)
#pragma unroll
      for (int nt = 0; nt < 2; ++nt) acc2[m][nt] = f32x4_t{0.f, 0.f, 0.f, 0.f};
    const uint4* w2f = (const uint4*)((const unsigned*)(wf + OW2P));
#pragma unroll 2
    for (int ks = 0; ks < 8; ++ks) {
      U4H8 bu[2];
#pragma unroll
      for (int nt = 0; nt < 2; ++nt) {
        int col = nt * 16 + (lane & 15);
        bu[nt].u = *(const uint4*)(hbb + ((col * 512 + ks * 64 + ((lane >> 4) << 4)) ^ ((col & 7) << 4)));
      }
#pragma unroll
      for (int m = 0; m < 4; ++m) {
        U4H8 a2;
        a2.u = w2f[((wid * 4 + m) * 8 + ks) * 64 + lane];
#pragma unroll
        for (int nt = 0; nt < 2; ++nt)
          acc2[m][nt] = mfma_16x16x32(a2.h, bu[nt].h, acc2[m][nt]);
      }
    }
#pragma unroll
    for (int m = 0; m < 4; ++m) {
      int ch0 = (wid * 4 + m) * 16 + ((lane >> 4) << 2);
      float4 bsv = *(const float4*)(wf + OBS2 + ch0);
#pragma unroll
      for (int nt = 0; nt < 2; ++nt) {
        int col = nt * 16 + (lane & 15);
        float v0 = acc2[m][nt][0] + accs[m][nt][0] + bsv.x;
        float v1 = acc2[m][nt][1] + accs[m][nt][1] + bsv.y;
        float v2 = acc2[m][nt][2] + accs[m][nt][2] + bsv.z;
        float v3 = acc2[m][nt][3] + accs[m][nt][3] + bsv.w;
        uint2 p;
        p.x = pkh2(v0, v1);
        p.y = pkh2(v2, v3);
        *(uint2*)(vbb + ((col * 512 + ch0 * 2) ^ ((col & 7) << 4))) = p;
      }
    }
  }
  __syncthreads();

  {
    f32x4_t accv[2], accr[2][2];
#pragma unroll
    for (int nt = 0; nt < 2; ++nt) {
      accv[nt] = f32x4_t{0.f, 0.f, 0.f, 0.f};
      accr[0][nt] = f32x4_t{0.f, 0.f, 0.f, 0.f};
      accr[1][nt] = f32x4_t{0.f, 0.f, 0.f, 0.f};
    }
    const uint4* wvf = (const uint4*)((const unsigned*)(wf + OWVP));
    const uint4* wrf = (const uint4*)((const unsigned*)(wf + OWRP));
#pragma unroll 2
    for (int ks = 0; ks < 8; ++ks) {
      U4H8 bu[2];
#pragma unroll
      for (int nt = 0; nt < 2; ++nt) {
        int col = nt * 16 + (lane & 15);
        bu[nt].u = *(const uint4*)(vbb + ((col * 512 + ks * 64 + ((lane >> 4) << 4)) ^ ((col & 7) << 4)));
      }
      U4H8 av;
      av.u = wvf[(wid * 8 + ks) * 64 + lane];
#pragma unroll
      for (int nt = 0; nt < 2; ++nt)
        accv[nt] = mfma_16x16x32(av.h, bu[nt].h, accv[nt]);
#pragma unroll
      for (int m2 = 0; m2 < 2; ++m2) {
        U4H8 ar;
        ar.u = wrf[((wid * 2 + m2) * 8 + ks) * 64 + lane];
#pragma unroll
        for (int nt = 0; nt < 2; ++nt)
          accr[m2][nt] = mfma_16x16x32(ar.h, bu[nt].h, accr[m2][nt]);
      }
    }
    {
      int ch0 = wid * 16 + ((lane >> 4) << 2);
      float4 bvv = *(const float4*)(wf + OBV + ch0);
#pragma unroll
      for (int nt = 0; nt < 2; ++nt) {
        int col = nt * 16 + (lane & 15);
        *(float4*)(vout + ((size_t)b * N_ + n0 + col) * 64 + ch0) =
            make_float4(accv[nt][0] + bvv.x, accv[nt][1] + bvv.y,
                        accv[nt][2] + bvv.z, accv[nt][3] + bvv.w);
      }
    }
#pragma unroll
    for (int m2 = 0; m2 < 2; ++m2) {
      int ch0 = (wid * 2 + m2) * 16 + ((lane >> 4) << 2);
      float4 brv = *(const float4*)(wf + OBR + ch0);
#pragma unroll
      for (int nt = 0; nt < 2; ++nt) {
        int col = nt * 16 + (lane & 15);
        *(float4*)(idenout + ((size_t)b * N_ + n0 + col) * 128 + ch0) =
            make_float4(accr[m2][nt][0] + brv.x, accr[m2][nt][1] + brv.y,
                        accr[m2][nt][2] + brv.z, accr[m2][nt][3] + brv.w);
      }
    }
  }
}

// ------------------------------------------------------------------
// u projection only (unchanged).
// ------------------------------------------------------------------
__global__ __launch_bounds__(256) void k_gemm_u(const float* __restrict__ wf,
                                                const float* __restrict__ x,
                                                float* __restrict__ out) {
  const int b = blockIdx.y;
  const int n0 = blockIdx.x * 64;
  const float* Wt = wf + OWUT;
  const float* bias = wf + OBU;
  __shared__ float ws_[16][64];
  __shared__ float xs_[16][64];
  const int tid = threadIdx.x, tm = tid & 15, tn = tid >> 4;
  float acc[4][4] = {};
  for (int kt = 0; kt < 256; kt += 16) {
    for (int i = tid; i < 1024; i += 256) {
      int kk = i >> 6, col = i & 63;
      ws_[kk][col] = Wt[(size_t)(kt + kk) * 64 + col];
      xs_[kk][col] = x[((size_t)b * 256 + kt + kk) * N_ + n0 + col];
    }
    __syncthreads();
#pragma unroll
    for (int kk = 0; kk < 16; ++kk) {
      float4 x4 = *(const float4*)&xs_[kk][tn * 4];
      float4 w4 = *(const float4*)&ws_[kk][tm * 4];
      float wv[4] = {w4.x, w4.y, w4.z, w4.w};
      float xv[4] = {x4.x, x4.y, x4.z, x4.w};
#pragma unroll
      for (int i = 0; i < 4; ++i)
#pragma unroll
        for (int j = 0; j < 4; ++j) acc[i][j] += wv[i] * xv[j];
    }
    __syncthreads();
  }
#pragma unroll
  for (int j = 0; j < 4; ++j) {
    *(float4*)(out + ((size_t)b * N_ + n0 + tn * 4 + j) * 64 + tm * 4) =
        make_float4(acc[0][j] + bias[tm * 4], acc[1][j] + bias[tm * 4 + 1],
                    acc[2][j] + bias[tm * 4 + 2], acc[3][j] + bias[tm * 4 + 3]);
  }
}

// ------------------------------------------------------------------
// Self-KNN v5 (unchanged): threshold + bitonic sort, exact.
// ------------------------------------------------------------------
__device__ __forceinline__ unsigned long long bitonic64_(unsigned long long v,
                                                         int lane) {
#pragma unroll
  for (int k = 2; k <= 64; k <<= 1) {
#pragma unroll
    for (int j = k >> 1; j > 0; j >>= 1) {
      unsigned long long o = (unsigned long long)__shfl_xor((long long)v, j);
      bool up = (lane & k) == 0;
      bool lower = (lane & j) == 0;
      bool keepmin = (lower == up);
      unsigned long long mn = o < v ? o : v;
      unsigned long long mx = o < v ? v : o;
      v = keepmin ? mn : mx;
    }
  }
  return v;
}

__global__ __launch_bounds__(256, 8) void k_knn(const float* __restrict__ pos,
                                                int* __restrict__ idxout) {
  const int b = blockIdx.x >> 11, n = blockIdx.x & 2047;
  __shared__ unsigned long long wkeys[4][20];
  __shared__ unsigned long long cand[4][64];
  const int tid = threadIdx.x;
  const int lane = tid & 63, wv = tid >> 6;
  const float* pb = pos + (size_t)b * 3 * N_;
  const double xq = pb[n], yq = pb[N_ + n], zq = pb[2 * N_ + n];
  const double sq = xq * xq + yq * yq + zq * zq;
  unsigned long long key[8];
#pragma unroll
  for (int s = 0; s < 8; ++s) {
    int i = tid + s * 256;
    double x = pb[i], y = pb[N_ + i], z = pb[2 * N_ + i];
    double psq = x * x + y * y + z * z;
    double dot = xq * x + yq * y + zq * z;
    double d2 = fmax((sq + psq) - 2.0 * dot, 0.0);
    key[s] = ((unsigned long long)__double_as_longlong(d2) & ~0x7FFull) |
             (unsigned long long)i;
  }
  unsigned long long m = key[0];
#pragma unroll
  for (int s = 1; s < 8; ++s) m = key[s] < m ? key[s] : m;

  unsigned long long v = bitonic64_(m, lane);
  unsigned long long T = (unsigned long long)__shfl((long long)v, 19);

  int c = 0;
#pragma unroll
  for (int s = 0; s < 8; ++s) c += (key[s] <= T) ? 1 : 0;
  int inc = c;
#pragma unroll
  for (int d = 1; d < 64; d <<= 1) {
    int t = __shfl_up(inc, d);
    if (lane >= d) inc += t;
  }
  const int C = __shfl(inc, 63);
  const int off = inc - c;

  if (C <= 64) {
    int o2 = off;
#pragma unroll
    for (int s = 0; s < 8; ++s) {
      if (key[s] <= T) { cand[wv][o2] = key[s]; ++o2; }
    }
    __builtin_amdgcn_wave_barrier();
    asm volatile("s_waitcnt lgkmcnt(0)" ::: "memory");
    unsigned long long cv = (lane < C) ? cand[wv][lane] : ~0ull;
    cv = bitonic64_(cv, lane);
    if (lane < K_) wkeys[wv][lane] = cv;
  } else {
    for (int r = 0; r < K_; ++r) {
      unsigned long long bk = key[0];
#pragma unroll
      for (int s = 1; s < 8; ++s) bk = key[s] < bk ? key[s] : bk;
      unsigned long long wk = bk;
#pragma unroll
      for (int mm = 32; mm; mm >>= 1) {
        unsigned long long ok = (unsigned long long)__shfl_xor((long long)wk, mm);
        if (ok < wk) wk = ok;
      }
      if (lane == 0) wkeys[wv][r] = wk;
      const int widx = (int)(wk & 0x7FF);
#pragma unroll
      for (int s = 0; s < 8; ++s)
        if (widx == tid + s * 256) key[s] = ~0ull;
    }
  }
  __syncthreads();

  if (tid < 128) {
    const int w = tid >> 5, p = tid & 31;
    if (p < 20) {
      const unsigned long long Kk = wkeys[w][p];
      int rank = p;
#pragma unroll
      for (int w2 = 0; w2 < 4; ++w2) {
        if (w2 == w) continue;
        int lo = 0, hi = 20;
        while (lo < hi) {
          int mid = (lo + hi) >> 1;
          if (wkeys[w2][mid] < Kk) lo = mid + 1; else hi = mid;
        }
        rank += lo;
      }
      if (rank < K_)
        idxout[((size_t)b * N_ + n) * K_ + rank] = (int)(Kk & 0x7FF);
    }
  }
}

// ------------------------------------------------------------------
// Fused attention tail v8: QB=2, un-chunked P4/P5 (no accumulators
// live across barriers -> no scratch spill; r12's 47KB/block spill
// traffic was acc5 persisting across the chunk loop at an 85-VGPR
// budget). Keeps v7's wins: P1 bases to LDS, P3 MFMA-epilogue folds
// pe in-place into S/sVal (pe buffer + P3b deleted), 40-row buffers.
// Padding-tile B-reads row-clamped (kc<40 ? kc : 0) to avoid reading
// actively-written LDS. LDS 32384 B -> 5 blocks/CU @ (256,5).
// Map (bytes): S(=base, in-place)@0 5120 | t1@5120 5120 |
//   h@5120..25600 (t1 dead) | lg f32[40][129]@0..20640 (S,t1,h dead)
//   | svb@25600 5120 | aggs@30720 1024 | idxs/pr@31744..32384.
// ------------------------------------------------------------------
__global__ __launch_bounds__(256, 5) void k_attn(
    const float* __restrict__ wf,
    const float* __restrict__ qb, const float* __restrict__ kb,
    const float* __restrict__ vb, const float* __restrict__ ub,
    const float* __restrict__ idenb, const int* __restrict__ idxb,
    const float* __restrict__ pos, float* __restrict__ out) {
  const int lb = ((int)blockIdx.x & 7) * 1024 + ((int)blockIdx.x >> 3);
  const int b = lb >> 10, n0 = (lb & 1023) * 2;
  const int tid = threadIdx.x;
  const int lane = tid & 63, wid = tid >> 6;

  __shared__ __align__(16) char smem[32384];
  char*  Sb   = smem;               // base -> S (in-place)
  char*  t1b  = smem + 5120;
  char*  hb   = smem + 5120;
  float* lg   = (float*)smem;
  char*  svb  = smem + 25600;       // base -> sVal (in-place)
  float* aggs = (float*)(smem + 30720);
  int*   idxs = (int*)(smem + 31744);
  float* prx  = (float*)(smem + 31904);
  float* pry  = (float*)(smem + 32064);
  float* prz  = (float*)(smem + 32224);

  if (tid < 40) {
    int qi = tid >= 20;
    idxs[tid] = idxb[((size_t)b * N_ + n0 + qi) * K_ + (tid - qi * 20)] & 2047;
  }
  __syncthreads();

  // P1: gathers -> base buffers f16 (swz). Wave w owns cols w*10..w*10+9.
  {
    const int qi = wid >> 1;
    size_t rowq = ((size_t)b * N_ + n0 + qi) * 64;
    float qvo = qb[rowq + lane];
    float ufo = ub[rowq + lane];
#pragma unroll
    for (int t = 0; t < 10; ++t) {
      int col = wid * 10 + t;
      int j = idxs[col];
      size_t rowj = ((size_t)b * N_ + j) * 64;
      float kvv = kb[rowj + lane], vvv = vb[rowj + lane], uvv = ub[rowj + lane];
      float ur = ufo - uvv;
      int ro = (col * 128 + lane * 2) ^ ((col & 7) << 4);
      *(_Float16*)(Sb + ro) = (_Float16)((qvo - kvv) + ur);
      *(_Float16*)(svb + ro) = (_Float16)(vvv + ur);
    }
    if (tid < 40) {
      int j = idxs[tid];
      int qn = n0 + (tid >= 20);
      const float* pp = pos + (size_t)b * 3 * N_;
      prx[tid] = pp[qn] - pp[j];
      pry[tid] = pp[N_ + qn] - pp[N_ + j];
      prz[tid] = pp[2 * N_ + qn] - pp[2 * N_ + j];
    }
  }
  __syncthreads();

  // P2: pos-MLP layer1 + BN + relu -> t1 f16 [col][ph] swz
  {
    int ph = lane;
    float w0 = wf[OPW1 + ph * 3], w1 = wf[OPW1 + ph * 3 + 1], w2 = wf[OPW1 + ph * 3 + 2];
    float pb1 = wf[OPB1 + ph], sc = wf[OPSC + ph], sh = wf[OPSH + ph];
#pragma unroll
    for (int t = 0; t < 10; ++t) {
      int col = wid * 10 + t;
      float u = pb1 + w0 * prx[col] + w1 * pry[col] + w2 * prz[col];
      float tv = fmaxf(u * sc + sh, 0.f);
      *(_Float16*)(t1b + ((col * 128 + ph * 2) ^ ((col & 7) << 4))) = (_Float16)tv;
    }
  }
  __syncthreads();

  // P3: pe = pm_w2 @ t1 via MFMA; epilogue folds pe into S/sVal in place
  {
    f32x4_t pacc[3];
#pragma unroll
    for (int nt = 0; nt < 3; ++nt) pacc[nt] = f32x4_t{0.f, 0.f, 0.f, 0.f};
    const int mt = wid;
#pragma unroll
    for (int ks = 0; ks < 2; ++ks) {
      U4H8 a;
      a.u = ((const uint4*)((const unsigned*)(wf + OPWF)))[(mt * 2 + ks) * 64 + lane];
#pragma unroll
      for (int nt = 0; nt < 3; ++nt) {
        int kc = nt * 16 + (lane & 15);
        int kr = kc < 40 ? kc : 0;
        U4H8 bu;
        bu.u = *(const uint4*)(t1b + ((kr * 128 + (ks * 32 + ((lane >> 4) << 3)) * 2) ^ ((kr & 7) << 4)));
        pacc[nt] = mfma_16x16x32(a.h, bu.h, pacc[nt]);
      }
    }
    const int o0 = mt * 16 + ((lane >> 4) << 2);
    float4 pb2v = *(const float4*)(wf + OPB2 + o0);
#pragma unroll
    for (int nt = 0; nt < 3; ++nt) {
      int kc = nt * 16 + (lane & 15);
      if (kc < 40) {
        int ro = (kc * 128 + o0 * 2) ^ ((kc & 7) << 4);
        float pe0 = pacc[nt][0] + pb2v.x, pe1 = pacc[nt][1] + pb2v.y;
        float pe2 = pacc[nt][2] + pb2v.z, pe3 = pacc[nt][3] + pb2v.w;
        _Float16* sp = (_Float16*)(Sb + ro);
        _Float16* vp = (_Float16*)(svb + ro);
        uint2 ps, pv;
        ps.x = pkh2((float)sp[0] + pe0, (float)sp[1] + pe1);
        ps.y = pkh2((float)sp[2] + pe2, (float)sp[3] + pe3);
        pv.x = pkh2((float)vp[0] + pe0, (float)vp[1] + pe1);
        pv.y = pkh2((float)vp[2] + pe2, (float)vp[3] + pe3);
        *(uint2*)sp = ps;
        *(uint2*)vp = pv;
      }
    }
  }
  __syncthreads();

  // P4: h = relu(bn(am_w1 @ S)), 16 mt over 2 passes, 3 nt; h [40][256]
#pragma unroll
  for (int pass = 0; pass < 2; ++pass) {
    const int mt0 = wid * 4 + pass * 2;
    f32x4_t acc[2][3];
#pragma unroll
    for (int m = 0; m < 2; ++m)
#pragma unroll
      for (int nt = 0; nt < 3; ++nt) acc[m][nt] = f32x4_t{0.f, 0.f, 0.f, 0.f};
#pragma unroll
    for (int ks = 0; ks < 2; ++ks) {
      U4H8 bfr[3];
#pragma unroll
      for (int nt = 0; nt < 3; ++nt) {
        int kc = nt * 16 + (lane & 15);
        int kr = kc < 40 ? kc : 0;
        bfr[nt].u = *(const uint4*)(Sb + ((kr * 128 + (ks * 32 + ((lane >> 4) << 3)) * 2) ^ ((kr & 7) << 4)));
      }
#pragma unroll
      for (int m = 0; m < 2; ++m) {
        U4H8 a;
        a.u = ((const uint4*)((const unsigned*)(wf + OAWF)))[((mt0 + m) * 2 + ks) * 64 + lane];
#pragma unroll
        for (int nt = 0; nt < 3; ++nt)
          acc[m][nt] = mfma_16x16x32(a.h, bfr[nt].h, acc[m][nt]);
      }
    }
#pragma unroll
    for (int m = 0; m < 2; ++m) {
      const int c0 = (mt0 + m) * 16 + ((lane >> 4) << 2);
      float4 ab1 = *(const float4*)(wf + OAB1 + c0);
      float4 asc = *(const float4*)(wf + OASC + c0);
      float4 ash = *(const float4*)(wf + OASH + c0);
#pragma unroll
      for (int nt = 0; nt < 3; ++nt) {
        int kc = nt * 16 + (lane & 15);
        if (kc < 40) {
          float h0 = fmaxf((acc[m][nt][0] + ab1.x) * asc.x + ash.x, 0.f);
          float h1 = fmaxf((acc[m][nt][1] + ab1.y) * asc.y + ash.y, 0.f);
          float h2 = fmaxf((acc[m][nt][2] + ab1.z) * asc.z + ash.z, 0.f);
          float h3 = fmaxf((acc[m][nt][3] + ab1.w) * asc.w + ash.w, 0.f);
          uint2 p;
          p.x = pkh2(h0, h1);
          p.y = pkh2(h2, h3);
          *(uint2*)(hb + ((kc * 512 + c0 * 2) ^ ((kc & 7) << 4))) = p;
        }
      }
    }
  }
  __syncthreads();

  // P5: lg = wt @ h (8 mt: wid*2+m, 8 ks, 3 nt); no barriers inside
  {
    f32x4_t acc5[2][3];
#pragma unroll
    for (int m = 0; m < 2; ++m)
#pragma unroll
      for (int nt = 0; nt < 3; ++nt) acc5[m][nt] = f32x4_t{0.f, 0.f, 0.f, 0.f};
#pragma unroll
    for (int ks = 0; ks < 8; ++ks) {
      U4H8 bfr[3];
#pragma unroll
      for (int nt = 0; nt < 3; ++nt) {
        int kc = nt * 16 + (lane & 15);
        int kr = kc < 40 ? kc : 0;
        bfr[nt].u = *(const uint4*)(hb + ((kr * 512 + (ks * 32 + ((lane >> 4) << 3)) * 2) ^ ((kr & 7) << 4)));
      }
#pragma unroll
      for (int m = 0; m < 2; ++m) {
        U4H8 a;
        a.u = ((const uint4*)((const unsigned*)(wf + OWTF)))[((wid * 2 + m) * 8 + ks) * 64 + lane];
#pragma unroll
        for (int nt = 0; nt < 3; ++nt)
          acc5[m][nt] = mfma_16x16x32(a.h, bfr[nt].h, acc5[m][nt]);
      }
    }
    __syncthreads();  // all S/h reads done before lg overlays them
#pragma unroll
    for (int m = 0; m < 2; ++m) {
      const int or0 = (wid * 2 + m) * 16 + ((lane >> 4) << 2);
#pragma unroll
      for (int nt = 0; nt < 3; ++nt) {
        int kc = nt * 16 + (lane & 15);
        if (kc < 40) {
#pragma unroll
          for (int r = 0; r < 4; ++r) lg[kc * 129 + or0 + r] = acc5[m][nt][r];
        }
      }
    }
  }
  __syncthreads();

  // P6: softmax over k + aggregate; all 256 threads (qsel = tid>>7)
  {
    const int qsel = tid >> 7, orr = tid & 127, o = orr >> 1;
    float l[20];
#pragma unroll
    for (int kk = 0; kk < 20; ++kk) l[kk] = lg[(qsel * 20 + kk) * 129 + orr];
    float bt = wf[OABT + o];
    float m = -3.4e38f;
#pragma unroll
    for (int kk = 0; kk < 20; ++kk) { l[kk] += bt; m = fmaxf(m, l[kk]); }
    float s = 0.f;
#pragma unroll
    for (int kk = 0; kk < 20; ++kk) { l[kk] = expf(l[kk] - m); s += l[kk]; }
    float inv = 1.f / s;
    float a = 0.f;
#pragma unroll
    for (int kk = 0; kk < 20; ++kk) {
      int row = qsel * 20 + kk;
      a += l[kk] * (float)(*(const _Float16*)(svb + ((row * 128 + o * 2) ^ ((row & 7) << 4))));
    }
    aggs[qsel * 128 + orr] = a * inv;
  }
  __syncthreads();

  // P7: y = we @ agg + be + iden; native we [co][o], float4
  {
    const int co = tid & 127, r = tid >> 7;
    float y0 = wf[OBE + co], y1 = y0;
    const float* w = wf + OWET + co * 64;
#pragma unroll 4
    for (int o4 = 0; o4 < 16; ++o4) {
      float4 w4 = *(const float4*)(w + o4 * 4);
      const float wv[4] = {w4.x, w4.y, w4.z, w4.w};
#pragma unroll
      for (int j = 0; j < 4; ++j) {
        int oi = o4 * 4 + j;
        y0 += wv[j] * aggs[oi * 2 + r];
        y1 += wv[j] * aggs[128 + oi * 2 + r];
      }
    }
    float id0 = idenb[((size_t)b * N_ + n0) * 128 + co];
    float id1 = idenb[((size_t)b * N_ + n0 + 1) * 128 + co];
    size_t obase = ((size_t)b * 128 + co) * (size_t)(2 * N_);
    out[obase + 2 * n0 + r] = y0 + id0;
    out[obase + 2 * n0 + 2 + r] = y1 + id1;
  }
}

extern "C" void kernel_launch(void* const* d_in, const int* in_sizes, int n_in,
                              void* d_out, int out_size, void* d_ws, size_t ws_size,
                              hipStream_t stream) {
  (void)in_sizes; (void)n_in; (void)out_size; (void)ws_size;
  InPtrs ip;
  for (int i = 0; i < 38; ++i) ip.p[i] = (const float*)d_in[i];
  char* ws = (char*)d_ws;
  float* wf    = (float*)(ws + OFFB_WF);
  int*   idxb  = (int*)(ws + OFFB_IDX);
  float* qb    = (float*)(ws + OFFB_Q);
  float* kb    = (float*)(ws + OFFB_K);
  float* ubuf  = (float*)(ws + OFFB_U);
  float* vbuf  = (float*)(ws + OFFB_V);
  float* idenb = (float*)(ws + OFFB_IDEN);

  k_prep<<<dim3(256), dim3(256), 0, stream>>>(ip, wf);
  k_mv<<<dim3(64, 8), dim3(256), 0, stream>>>(wf, ip.p[1], ip.p[2], vbuf, idenb, qb, kb);
  k_gemm_u<<<dim3(32, 8), dim3(256), 0, stream>>>(wf, ip.p[3], ubuf);
  k_knn<<<dim3(B_ * N_), dim3(256), 0, stream>>>(ip.p[0], idxb);
  k_attn<<<dim3(B_ * N_ / 2), dim3(256), 0, stream>>>(wf, qb, kb, vbuf, ubuf, idenb, idxb,
                                                      ip.p[0], (float*)d_out);
}

// Round 14
// 412.546 us; speedup vs baseline: 1.1894x; 1.0934x over previous
//
#include <hip/hip_runtime.h>
#include <hip/hip_bf16.h>

constexpr int B_ = 8, N_ = 2048, K_ = 20;
constexpr float EPS_ = 1e-5f;

// ---- weight area offsets (float slots; "u" = uint32 of packed half2) ----
// matrices stored as MFMA A-fragments (16x16x32 f16):
// frag index ((mt*KS+ks)*64+l)*4+q -> m = mt*16+(l&15), k = ks*32+(l>>4)*8+2q
constexpr int OW1P = 0;                    // u W1 frags  mt16 ks16 = 65536u
constexpr int OWSP = OW1P + 256 * 256;     // u Ws frags  65536u
constexpr int OW2P = OWSP + 256 * 256;     // u W2 frags  mt16 ks8 = 32768u
constexpr int OWVP = OW2P + 128 * 256;     // u wv frags  mt4 ks8 = 8192u
constexpr int OWRP = OWVP + 128 * 64;      // u wr frags  mt8 ks8 = 16384u
constexpr int OWQT = OWRP + 128 * 128;     // u wq frags  mt4 ks8 = 8192u
constexpr int OWKT = OWQT + 256 * 64;      // u wk frags  8192u
constexpr int OWUT = OWKT + 256 * 64;      // u wu frags  mt4 ks8 = 8192u (16384-slot)
constexpr int OWET = OWUT + 256 * 64;      // f32 we NATIVE [co 128][o 64]
constexpr int OWTF = OWET + 64 * 128;      // u  wt A-frags  [mt8][ks8][l64]x4u
constexpr int OAWF = OWTF + 16384;         // u  am_w1 A-frags [mt16][ks2][l64]x4u
constexpr int OPWF = OAWF + 8192;          // u  pm_w2 A-frags [mt4][ks2][l64]x4u
constexpr int OPW1 = OPWF + 2048;          // pm_w1 [ph][3]
constexpr int OB1  = OPW1 + 192;           // mv_b1 [256]
constexpr int OBS2 = OB1 + 256;            // mv_bs + mv_b2 [256]
constexpr int OBQ  = OBS2 + 256;
constexpr int OBK  = OBQ + 64;
constexpr int OBV  = OBK + 64;
constexpr int OBU  = OBV + 64;
constexpr int OBR  = OBU + 64;             // [128]
constexpr int OBE  = OBR + 128;            // [128]
constexpr int OPB1 = OBE + 128;            // [64]
constexpr int OPSC = OPB1 + 64;
constexpr int OPSH = OPSC + 64;
constexpr int OPB2 = OPSH + 64;
constexpr int OASC = OPB2 + 64;            // [256]
constexpr int OASH = OASC + 256;
constexpr int OAB1 = OASH + 256;
constexpr int OABT = OAB1 + 256;           // [64]

// ---- workspace byte offsets (28 MiB total) ----
constexpr size_t OFFB_WF   = 0;
constexpr size_t OFFB_IDX  = (size_t)2 << 20;
constexpr size_t OFFB_Q    = (size_t)4 << 20;   // [b][n][64]
constexpr size_t OFFB_K    = (size_t)8 << 20;   // [b][n][64]
constexpr size_t OFFB_U    = (size_t)12 << 20;  // [b][n][64]
constexpr size_t OFFB_V    = (size_t)16 << 20;  // [b][n][64]
constexpr size_t OFFB_IDEN = (size_t)20 << 20;  // [b][n][128]

struct InPtrs { const float* p[38]; };

// ---- f16 helpers ----
typedef _Float16 half2_t __attribute__((ext_vector_type(2)));
typedef _Float16 f16x8_t __attribute__((ext_vector_type(8)));
typedef float    f32x4_t __attribute__((ext_vector_type(4)));

union U4H8 { uint4 u; f16x8_t h; };

__device__ __forceinline__ unsigned pkh2(float a, float b) {
  union { unsigned u; half2_t h; } x;
  x.h = half2_t{(_Float16)a, (_Float16)b};
  return x.u;
}
__device__ __forceinline__ f32x4_t mfma_16x16x32(f16x8_t a, f16x8_t b, f32x4_t c) {
  return __builtin_amdgcn_mfma_f32_16x16x32_f16(a, b, c, 0, 0, 0);
}

// ------------------------------------------------------------------
// Weight prep: A-fragment packs for mv/q/k/u/attn, BN folds.
// ------------------------------------------------------------------
__global__ __launch_bounds__(256) void k_prep(InPtrs in, float* __restrict__ wf) {
  const int tid = blockIdx.x * 256 + threadIdx.x;
  const int nth = gridDim.x * 256;
  const float *mv_w1 = in.p[4], *mv_b1 = in.p[5], *mv_w2 = in.p[6], *mv_b2 = in.p[7],
              *mv_ws = in.p[8], *mv_bs = in.p[9], *wk = in.p[10], *bk = in.p[11],
              *wq = in.p[12], *bq = in.p[13], *wv = in.p[14], *bv = in.p[15],
              *wu = in.p[16], *bu = in.p[17], *pm_w1 = in.p[18], *pm_b1 = in.p[19],
              *pm_g = in.p[20], *pm_be = in.p[21], *pm_m = in.p[22], *pm_v = in.p[23],
              *pm_w2 = in.p[24], *pm_b2 = in.p[25], *am_w1 = in.p[26], *am_b1 = in.p[27],
              *am_g = in.p[28], *am_be = in.p[29], *am_m = in.p[30], *am_v = in.p[31],
              *am_wt = in.p[32], *am_bt = in.p[33], *we = in.p[34], *be = in.p[35],
              *wr = in.p[36], *br = in.p[37];

  {
    unsigned* w1f = (unsigned*)(wf + OW1P);
    for (int i = tid; i < 65536; i += nth) {
      int q = i & 3, l = (i >> 2) & 63, ks = (i >> 8) & 15, mt = i >> 12;
      int m = mt * 16 + (l & 15);
      int k = ks * 32 + ((l >> 4) << 3) + 2 * q;
      w1f[i] = pkh2(mv_w1[m * 512 + k], mv_w1[m * 512 + k + 1]);
    }
    unsigned* wsf = (unsigned*)(wf + OWSP);
    for (int i = tid; i < 65536; i += nth) {
      int q = i & 3, l = (i >> 2) & 63, ks = (i >> 8) & 15, mt = i >> 12;
      int m = mt * 16 + (l & 15);
      int k = ks * 32 + ((l >> 4) << 3) + 2 * q;
      wsf[i] = pkh2(mv_ws[m * 512 + k], mv_ws[m * 512 + k + 1]);
    }
    unsigned* w2f = (unsigned*)(wf + OW2P);
    for (int i = tid; i < 32768; i += nth) {
      int q = i & 3, l = (i >> 2) & 63, ks = (i >> 8) & 7, mt = i >> 11;
      int m = mt * 16 + (l & 15);
      int k = ks * 32 + ((l >> 4) << 3) + 2 * q;
      w2f[i] = pkh2(mv_w2[m * 256 + k], mv_w2[m * 256 + k + 1]);
    }
    unsigned* wvf = (unsigned*)(wf + OWVP);
    for (int i = tid; i < 8192; i += nth) {
      int q = i & 3, l = (i >> 2) & 63, ks = (i >> 8) & 7, mt = i >> 11;
      int m = mt * 16 + (l & 15);
      int k = ks * 32 + ((l >> 4) << 3) + 2 * q;
      wvf[i] = pkh2(wv[m * 256 + k], wv[m * 256 + k + 1]);
    }
    unsigned* wrf = (unsigned*)(wf + OWRP);
    for (int i = tid; i < 16384; i += nth) {
      int q = i & 3, l = (i >> 2) & 63, ks = (i >> 8) & 7, mt = i >> 11;
      int m = mt * 16 + (l & 15);
      int k = ks * 32 + ((l >> 4) << 3) + 2 * q;
      wrf[i] = pkh2(wr[m * 256 + k], wr[m * 256 + k + 1]);
    }
    unsigned* wqf = (unsigned*)(wf + OWQT);
    for (int i = tid; i < 8192; i += nth) {
      int q = i & 3, l = (i >> 2) & 63, ks = (i >> 8) & 7, mt = i >> 11;
      int m = mt * 16 + (l & 15);
      int k = ks * 32 + ((l >> 4) << 3) + 2 * q;
      wqf[i] = pkh2(wq[m * 256 + k], wq[m * 256 + k + 1]);
    }
    unsigned* wkf = (unsigned*)(wf + OWKT);
    for (int i = tid; i < 8192; i += nth) {
      int q = i & 3, l = (i >> 2) & 63, ks = (i >> 8) & 7, mt = i >> 11;
      int m = mt * 16 + (l & 15);
      int k = ks * 32 + ((l >> 4) << 3) + 2 * q;
      wkf[i] = pkh2(wk[m * 256 + k], wk[m * 256 + k + 1]);
    }
    unsigned* wuf = (unsigned*)(wf + OWUT);
    for (int i = tid; i < 8192; i += nth) {
      int q = i & 3, l = (i >> 2) & 63, ks = (i >> 8) & 7, mt = i >> 11;
      int m = mt * 16 + (l & 15);
      int k = ks * 32 + ((l >> 4) << 3) + 2 * q;
      wuf[i] = pkh2(wu[m * 256 + k], wu[m * 256 + k + 1]);
    }
  }
  for (int i = tid; i < 64 * 128; i += nth) wf[OWET + i] = we[i];  // native [co][o]

  {
    unsigned* wtf = (unsigned*)(wf + OWTF);
    for (int i = tid; i < 16384; i += nth) {
      int q = i & 3, l = (i >> 2) & 63, ks = (i >> 8) & 7, mt = i >> 11;
      int orr = mt * 16 + (l & 15);
      int c = ks * 32 + ((l >> 4) << 3) + 2 * q;
      wtf[i] = pkh2(am_wt[c * 128 + orr], am_wt[(c + 1) * 128 + orr]);
    }
  }
  {
    unsigned* awf = (unsigned*)(wf + OAWF);
    for (int i = tid; i < 8192; i += nth) {
      int q = i & 3, l = (i >> 2) & 63, ks = (i >> 8) & 1, mt = i >> 9;
      int c = mt * 16 + (l & 15);
      int o = ks * 32 + ((l >> 4) << 3) + 2 * q;
      awf[i] = pkh2(am_w1[c * 64 + o], am_w1[c * 64 + o + 1]);
    }
  }
  {
    unsigned* pwf = (unsigned*)(wf + OPWF);
    for (int i = tid; i < 2048; i += nth) {
      int q = i & 3, l = (i >> 2) & 63, ks = (i >> 8) & 1, mt = i >> 9;
      int o = mt * 16 + (l & 15);
      int ph = ks * 32 + ((l >> 4) << 3) + 2 * q;
      pwf[i] = pkh2(pm_w2[o * 64 + ph], pm_w2[o * 64 + ph + 1]);
    }
  }
  for (int i = tid; i < 192; i += nth) wf[OPW1 + i] = pm_w1[i];
  for (int i = tid; i < 256; i += nth) {
    wf[OB1 + i] = mv_b1[i];
    wf[OBS2 + i] = mv_bs[i] + mv_b2[i];
    float sc = am_g[i] / sqrtf(am_v[i] + EPS_);
    wf[OASC + i] = sc;
    wf[OASH + i] = am_be[i] - am_m[i] * sc;
    wf[OAB1 + i] = am_b1[i];
  }
  for (int i = tid; i < 64; i += nth) {
    wf[OBQ + i] = bq[i]; wf[OBK + i] = bk[i];
    wf[OBV + i] = bv[i]; wf[OBU + i] = bu[i];
    wf[OABT + i] = am_bt[i]; wf[OPB1 + i] = pm_b1[i]; wf[OPB2 + i] = pm_b2[i];
    float sc = pm_g[i] / sqrtf(pm_v[i] + EPS_);
    wf[OPSC + i] = sc;
    wf[OPSH + i] = pm_be[i] - pm_m[i] * sc;
  }
  for (int i = tid; i < 128; i += nth) { wf[OBR + i] = br[i]; wf[OBE + i] = be[i]; }
}

// ------------------------------------------------------------------
// Fused mv-MLP v4: all 5 mv GEMMs + q/k/u projections on MFMA.
// u-projection folded in: upfeat staged as f16 [32][256] swz (+16KB),
// 16 extra MFMA/wave, u-GEMM runs while uxs is live. 64KB LDS ->
// 2 blocks/CU (unchanged). k_gemm_u kernel deleted.
// ------------------------------------------------------------------
__global__ __launch_bounds__(256, 2) void k_mv(const float* __restrict__ wf,
                                               const float* __restrict__ keyf,
                                               const float* __restrict__ qryf,
                                               const float* __restrict__ upf,
                                               float* __restrict__ vout,
                                               float* __restrict__ idenout,
                                               float* __restrict__ qout,
                                               float* __restrict__ kout,
                                               float* __restrict__ uout) {
  const int b = blockIdx.y;
  const int n0 = blockIdx.x * 32;
  const int tid = threadIdx.x, lane = tid & 63, wid = tid >> 6;
  __shared__ __align__(16) char smem[65536];
  char* xsb = smem;                 // [32][512] f16, 32KB
  char* hbb = smem + 32768;         // [32][256] f16, 16KB
  char* uxs = smem + 49152;         // [32][256] f16, 16KB
  char* vbb = smem;                 // val overlays xs after GEMM2

  // stage xs (key|qry) and uxs (upfeat)
  {
    const int col = tid & 31, kq = tid >> 5;
    const int swz = (col & 7) << 4;
#pragma unroll 4
    for (int it = 0; it < 32; ++it) {
      int k2 = it * 8 + kq;
      int c = 2 * k2;
      const float* s = (c < 256) ? keyf : qryf;
      size_t base = ((size_t)b * 256 + (c & 255)) * N_ + n0 + col;
      float x0 = s[base], x1 = s[base + N_];
      *(unsigned*)(xsb + ((col * 1024 + k2 * 4) ^ swz)) = pkh2(x0, x1);
    }
#pragma unroll 4
    for (int it = 0; it < 16; ++it) {
      int k2 = it * 8 + kq;
      size_t base = ((size_t)b * 256 + 2 * k2) * N_ + n0 + col;
      float x0 = upf[base], x1 = upf[base + N_];
      *(unsigned*)(uxs + ((col * 512 + k2 * 4) ^ swz)) = pkh2(x0, x1);
    }
  }
  __syncthreads();

  f32x4_t acch[4][2], accs[4][2];
#pragma unroll
  for (int m = 0; m < 4; ++m)
#pragma unroll
    for (int nt = 0; nt < 2; ++nt) {
      acch[m][nt] = f32x4_t{0.f, 0.f, 0.f, 0.f};
      accs[m][nt] = f32x4_t{0.f, 0.f, 0.f, 0.f};
    }
  {
    const uint4* w1f = (const uint4*)((const unsigned*)(wf + OW1P));
    const uint4* wsf = (const uint4*)((const unsigned*)(wf + OWSP));
#pragma unroll 2
    for (int ks = 0; ks < 16; ++ks) {
      U4H8 bu[2];
#pragma unroll
      for (int nt = 0; nt < 2; ++nt) {
        int col = nt * 16 + (lane & 15);
        bu[nt].u = *(const uint4*)(xsb + ((col * 1024 + ks * 64 + ((lane >> 4) << 4)) ^ ((col & 7) << 4)));
      }
#pragma unroll
      for (int m = 0; m < 4; ++m) {
        U4H8 a1, as_;
        a1.u = w1f[((wid * 4 + m) * 16 + ks) * 64 + lane];
        as_.u = wsf[((wid * 4 + m) * 16 + ks) * 64 + lane];
#pragma unroll
        for (int nt = 0; nt < 2; ++nt) {
          acch[m][nt] = mfma_16x16x32(a1.h, bu[nt].h, acch[m][nt]);
          accs[m][nt] = mfma_16x16x32(as_.h, bu[nt].h, accs[m][nt]);
        }
      }
    }
  }
#pragma unroll
  for (int m = 0; m < 4; ++m) {
    int ch0 = (wid * 4 + m) * 16 + ((lane >> 4) << 2);
    float4 b1v = *(const float4*)(wf + OB1 + ch0);
#pragma unroll
    for (int nt = 0; nt < 2; ++nt) {
      int col = nt * 16 + (lane & 15);
      float h0 = fmaxf(acch[m][nt][0] + b1v.x, 0.f);
      float h1 = fmaxf(acch[m][nt][1] + b1v.y, 0.f);
      float h2 = fmaxf(acch[m][nt][2] + b1v.z, 0.f);
      float h3 = fmaxf(acch[m][nt][3] + b1v.w, 0.f);
      uint2 p;
      p.x = pkh2(h0, h1);
      p.y = pkh2(h2, h3);
      *(uint2*)(hbb + ((col * 512 + ch0 * 2) ^ ((col & 7) << 4))) = p;
    }
  }

  // q/k GEMMs (xs live) + u GEMM (uxs live)
  {
    f32x4_t accq[2], acck[2], accu[2];
#pragma unroll
    for (int nt = 0; nt < 2; ++nt) {
      accq[nt] = f32x4_t{0.f, 0.f, 0.f, 0.f};
      acck[nt] = f32x4_t{0.f, 0.f, 0.f, 0.f};
      accu[nt] = f32x4_t{0.f, 0.f, 0.f, 0.f};
    }
    const uint4* wqf = (const uint4*)((const unsigned*)(wf + OWQT));
    const uint4* wkf = (const uint4*)((const unsigned*)(wf + OWKT));
    const uint4* wuf = (const uint4*)((const unsigned*)(wf + OWUT));
#pragma unroll 2
    for (int ks8 = 0; ks8 < 8; ++ks8) {
      U4H8 bk_[2], bq_[2], bu_[2];
#pragma unroll
      for (int nt = 0; nt < 2; ++nt) {
        int col = nt * 16 + (lane & 15);
        int swz = (col & 7) << 4;
        bk_[nt].u = *(const uint4*)(xsb + ((col * 1024 + ks8 * 64 + ((lane >> 4) << 4)) ^ swz));
        bq_[nt].u = *(const uint4*)(xsb + ((col * 1024 + (8 + ks8) * 64 + ((lane >> 4) << 4)) ^ swz));
        bu_[nt].u = *(const uint4*)(uxs + ((col * 512 + ks8 * 64 + ((lane >> 4) << 4)) ^ swz));
      }
      U4H8 aq, ak, au;
      aq.u = wqf[(wid * 8 + ks8) * 64 + lane];
      ak.u = wkf[(wid * 8 + ks8) * 64 + lane];
      au.u = wuf[(wid * 8 + ks8) * 64 + lane];
#pragma unroll
      for (int nt = 0; nt < 2; ++nt) {
        acck[nt] = mfma_16x16x32(ak.h, bk_[nt].h, acck[nt]);
        accq[nt] = mfma_16x16x32(aq.h, bq_[nt].h, accq[nt]);
        accu[nt] = mfma_16x16x32(au.h, bu_[nt].h, accu[nt]);
      }
    }
    int ch0 = wid * 16 + ((lane >> 4) << 2);
    float4 bqv = *(const float4*)(wf + OBQ + ch0);
    float4 bkv = *(const float4*)(wf + OBK + ch0);
    float4 buv = *(const float4*)(wf + OBU + ch0);
#pragma unroll
    for (int nt = 0; nt < 2; ++nt) {
      int col = nt * 16 + (lane & 15);
      *(float4*)(qout + ((size_t)b * N_ + n0 + col) * 64 + ch0) =
          make_float4(accq[nt][0] + bqv.x, accq[nt][1] + bqv.y,
                      accq[nt][2] + bqv.z, accq[nt][3] + bqv.w);
      *(float4*)(kout + ((size_t)b * N_ + n0 + col) * 64 + ch0) =
          make_float4(acck[nt][0] + bkv.x, acck[nt][1] + bkv.y,
                      acck[nt][2] + bkv.z, acck[nt][3] + bkv.w);
      *(float4*)(uout + ((size_t)b * N_ + n0 + col) * 64 + ch0) =
          make_float4(accu[nt][0] + buv.x, accu[nt][1] + buv.y,
                      accu[nt][2] + buv.z, accu[nt][3] + buv.w);
    }
  }
  __syncthreads();

  {
    f32x4_t acc2[4][2];
#pragma unroll
    for (int m = 0; m < 4; ++m)
#pragma unroll
      for (int nt = 0; nt < 2; ++nt) acc2[m][nt] = f32x4_t{0.f, 0.f, 0.f, 0.f};
    const uint4* w2f = (const uint4*)((const unsigned*)(wf + OW2P));
#pragma unroll 2
    for (int ks = 0; ks < 8; ++ks) {
      U4H8 bu[2];
#pragma unroll
      for (int nt = 0; nt < 2; ++nt) {
        int col = nt * 16 + (lane & 15);
        bu[nt].u = *(const uint4*)(hbb + ((col * 512 + ks * 64 + ((lane >> 4) << 4)) ^ ((col & 7) << 4)));
      }
#pragma unroll
      for (int m = 0; m < 4; ++m) {
        U4H8 a2;
        a2.u = w2f[((wid * 4 + m) * 8 + ks) * 64 + lane];
#pragma unroll
        for (int nt = 0; nt < 2; ++nt)
          acc2[m][nt] = mfma_16x16x32(a2.h, bu[nt].h, acc2[m][nt]);
      }
    }
#pragma unroll
    for (int m = 0; m < 4; ++m) {
      int ch0 = (wid * 4 + m) * 16 + ((lane >> 4) << 2);
      float4 bsv = *(const float4*)(wf + OBS2 + ch0);
#pragma unroll
      for (int nt = 0; nt < 2; ++nt) {
        int col = nt * 16 + (lane & 15);
        float v0 = acc2[m][nt][0] + accs[m][nt][0] + bsv.x;
        float v1 = acc2[m][nt][1] + accs[m][nt][1] + bsv.y;
        float v2 = acc2[m][nt][2] + accs[m][nt][2] + bsv.z;
        float v3 = acc2[m][nt][3] + accs[m][nt][3] + bsv.w;
        uint2 p;
        p.x = pkh2(v0, v1);
        p.y = pkh2(v2, v3);
        *(uint2*)(vbb + ((col * 512 + ch0 * 2) ^ ((col & 7) << 4))) = p;
      }
    }
  }
  __syncthreads();

  {
    f32x4_t accv[2], accr[2][2];
#pragma unroll
    for (int nt = 0; nt < 2; ++nt) {
      accv[nt] = f32x4_t{0.f, 0.f, 0.f, 0.f};
      accr[0][nt] = f32x4_t{0.f, 0.f, 0.f, 0.f};
      accr[1][nt] = f32x4_t{0.f, 0.f, 0.f, 0.f};
    }
    const uint4* wvf = (const uint4*)((const unsigned*)(wf + OWVP));
    const uint4* wrf = (const uint4*)((const unsigned*)(wf + OWRP));
#pragma unroll 2
    for (int ks = 0; ks < 8; ++ks) {
      U4H8 bu[2];
#pragma unroll
      for (int nt = 0; nt < 2; ++nt) {
        int col = nt * 16 + (lane & 15);
        bu[nt].u = *(const uint4*)(vbb + ((col * 512 + ks * 64 + ((lane >> 4) << 4)) ^ ((col & 7) << 4)));
      }
      U4H8 av;
      av.u = wvf[(wid * 8 + ks) * 64 + lane];
#pragma unroll
      for (int nt = 0; nt < 2; ++nt)
        accv[nt] = mfma_16x16x32(av.h, bu[nt].h, accv[nt]);
#pragma unroll
      for (int m2 = 0; m2 < 2; ++m2) {
        U4H8 ar;
        ar.u = wrf[((wid * 2 + m2) * 8 + ks) * 64 + lane];
#pragma unroll
        for (int nt = 0; nt < 2; ++nt)
          accr[m2][nt] = mfma_16x16x32(ar.h, bu[nt].h, accr[m2][nt]);
      }
    }
    {
      int ch0 = wid * 16 + ((lane >> 4) << 2);
      float4 bvv = *(const float4*)(wf + OBV + ch0);
#pragma unroll
      for (int nt = 0; nt < 2; ++nt) {
        int col = nt * 16 + (lane & 15);
        *(float4*)(vout + ((size_t)b * N_ + n0 + col) * 64 + ch0) =
            make_float4(accv[nt][0] + bvv.x, accv[nt][1] + bvv.y,
                        accv[nt][2] + bvv.z, accv[nt][3] + bvv.w);
      }
    }
#pragma unroll
    for (int m2 = 0; m2 < 2; ++m2) {
      int ch0 = (wid * 2 + m2) * 16 + ((lane >> 4) << 2);
      float4 brv = *(const float4*)(wf + OBR + ch0);
#pragma unroll
      for (int nt = 0; nt < 2; ++nt) {
        int col = nt * 16 + (lane & 15);
        *(float4*)(idenout + ((size_t)b * N_ + n0 + col) * 128 + ch0) =
            make_float4(accr[m2][nt][0] + brv.x, accr[m2][nt][1] + brv.y,
                        accr[m2][nt][2] + brv.z, accr[m2][nt][3] + brv.w);
      }
    }
  }
}

// ------------------------------------------------------------------
// Self-KNN v5 (unchanged): threshold + bitonic sort, exact.
// ------------------------------------------------------------------
__device__ __forceinline__ unsigned long long bitonic64_(unsigned long long v,
                                                         int lane) {
#pragma unroll
  for (int k = 2; k <= 64; k <<= 1) {
#pragma unroll
    for (int j = k >> 1; j > 0; j >>= 1) {
      unsigned long long o = (unsigned long long)__shfl_xor((long long)v, j);
      bool up = (lane & k) == 0;
      bool lower = (lane & j) == 0;
      bool keepmin = (lower == up);
      unsigned long long mn = o < v ? o : v;
      unsigned long long mx = o < v ? v : o;
      v = keepmin ? mn : mx;
    }
  }
  return v;
}

__global__ __launch_bounds__(256, 8) void k_knn(const float* __restrict__ pos,
                                                int* __restrict__ idxout) {
  const int b = blockIdx.x >> 11, n = blockIdx.x & 2047;
  __shared__ unsigned long long wkeys[4][20];
  __shared__ unsigned long long cand[4][64];
  const int tid = threadIdx.x;
  const int lane = tid & 63, wv = tid >> 6;
  const float* pb = pos + (size_t)b * 3 * N_;
  const double xq = pb[n], yq = pb[N_ + n], zq = pb[2 * N_ + n];
  const double sq = xq * xq + yq * yq + zq * zq;
  unsigned long long key[8];
#pragma unroll
  for (int s = 0; s < 8; ++s) {
    int i = tid + s * 256;
    double x = pb[i], y = pb[N_ + i], z = pb[2 * N_ + i];
    double psq = x * x + y * y + z * z;
    double dot = xq * x + yq * y + zq * z;
    double d2 = fmax((sq + psq) - 2.0 * dot, 0.0);
    key[s] = ((unsigned long long)__double_as_longlong(d2) & ~0x7FFull) |
             (unsigned long long)i;
  }
  unsigned long long m = key[0];
#pragma unroll
  for (int s = 1; s < 8; ++s) m = key[s] < m ? key[s] : m;

  unsigned long long v = bitonic64_(m, lane);
  unsigned long long T = (unsigned long long)__shfl((long long)v, 19);

  int c = 0;
#pragma unroll
  for (int s = 0; s < 8; ++s) c += (key[s] <= T) ? 1 : 0;
  int inc = c;
#pragma unroll
  for (int d = 1; d < 64; d <<= 1) {
    int t = __shfl_up(inc, d);
    if (lane >= d) inc += t;
  }
  const int C = __shfl(inc, 63);
  const int off = inc - c;

  if (C <= 64) {
    int o2 = off;
#pragma unroll
    for (int s = 0; s < 8; ++s) {
      if (key[s] <= T) { cand[wv][o2] = key[s]; ++o2; }
    }
    __builtin_amdgcn_wave_barrier();
    asm volatile("s_waitcnt lgkmcnt(0)" ::: "memory");
    unsigned long long cv = (lane < C) ? cand[wv][lane] : ~0ull;
    cv = bitonic64_(cv, lane);
    if (lane < K_) wkeys[wv][lane] = cv;
  } else {
    for (int r = 0; r < K_; ++r) {
      unsigned long long bk = key[0];
#pragma unroll
      for (int s = 1; s < 8; ++s) bk = key[s] < bk ? key[s] : bk;
      unsigned long long wk = bk;
#pragma unroll
      for (int mm = 32; mm; mm >>= 1) {
        unsigned long long ok = (unsigned long long)__shfl_xor((long long)wk, mm);
        if (ok < wk) wk = ok;
      }
      if (lane == 0) wkeys[wv][r] = wk;
      const int widx = (int)(wk & 0x7FF);
#pragma unroll
      for (int s = 0; s < 8; ++s)
        if (widx == tid + s * 256) key[s] = ~0ull;
    }
  }
  __syncthreads();

  if (tid < 128) {
    const int w = tid >> 5, p = tid & 31;
    if (p < 20) {
      const unsigned long long Kk = wkeys[w][p];
      int rank = p;
#pragma unroll
      for (int w2 = 0; w2 < 4; ++w2) {
        if (w2 == w) continue;
        int lo = 0, hi = 20;
        while (lo < hi) {
          int mid = (lo + hi) >> 1;
          if (wkeys[w2][mid] < Kk) lo = mid + 1; else hi = mid;
        }
        rank += lo;
      }
      if (rank < K_)
        idxout[((size_t)b * N_ + n) * K_ + rank] = (int)(Kk & 0x7FF);
    }
  }
}

// ------------------------------------------------------------------
// Fused attention tail v6 (round-11 version, reverted verbatim —
// best measured k_attn at 162 us; v7/v8 LDS diets both regressed).
// ------------------------------------------------------------------
__global__ __launch_bounds__(256, 4) void k_attn(
    const float* __restrict__ wf,
    const float* __restrict__ qb, const float* __restrict__ kb,
    const float* __restrict__ vb, const float* __restrict__ ub,
    const float* __restrict__ idenb, const int* __restrict__ idxb,
    const float* __restrict__ pos, float* __restrict__ out) {
  const int lb = ((int)blockIdx.x & 7) * 1024 + ((int)blockIdx.x >> 3);
  const int b = lb >> 10, n0 = (lb & 1023) * 2;
  const int tid = threadIdx.x;
  const int lane = tid & 63, wid = tid >> 6;

  __shared__ __align__(16) char smem[38528];
  char*  Sb   = smem;
  char*  hb   = smem + 6144;
  char*  t1b  = smem + 6144;
  char*  peb  = smem + 12288;
  float* lg   = (float*)(smem + 6144);
  char*  svb  = smem + 30720;
  float* aggs = (float*)(smem + 36864);
  int*   idxs = (int*)(smem + 37888);
  float* prx  = (float*)(smem + 38048);
  float* pry  = (float*)(smem + 38208);
  float* prz  = (float*)(smem + 38368);

  if (tid < 40) {
    int qi = tid >= 20;
    idxs[tid] = idxb[((size_t)b * N_ + n0 + qi) * K_ + (tid - qi * 20)] & 2047;
  }
  __syncthreads();

  // P1: gathers; wave w owns cols w*10..w*10+9 (all one query: qi=wid>>1)
  float sreg[10], vreg[10];
  {
    const int qi = wid >> 1;
    size_t rowq = ((size_t)b * N_ + n0 + qi) * 64;
    float qvo = qb[rowq + lane];
    float ufo = ub[rowq + lane];
#pragma unroll
    for (int t = 0; t < 10; ++t) {
      int col = wid * 10 + t;
      int j = idxs[col];
      size_t rowj = ((size_t)b * N_ + j) * 64;
      float kvv = kb[rowj + lane], vvv = vb[rowj + lane], uvv = ub[rowj + lane];
      float ur = ufo - uvv;
      sreg[t] = (qvo - kvv) + ur;
      vreg[t] = vvv + ur;
    }
    if (tid < 40) {
      int j = idxs[tid];
      int qn = n0 + (tid >= 20);
      const float* pp = pos + (size_t)b * 3 * N_;
      prx[tid] = pp[qn] - pp[j];
      pry[tid] = pp[N_ + qn] - pp[N_ + j];
      prz[tid] = pp[2 * N_ + qn] - pp[2 * N_ + j];
    }
  }
  __syncthreads();

  // P2: pos-MLP layer1 + BN + relu -> t1 f16 [col][ph] swz
  {
    int ph = lane;
    float w0 = wf[OPW1 + ph * 3], w1 = wf[OPW1 + ph * 3 + 1], w2 = wf[OPW1 + ph * 3 + 2];
    float pb1 = wf[OPB1 + ph], sc = wf[OPSC + ph], sh = wf[OPSH + ph];
#pragma unroll
    for (int t = 0; t < 10; ++t) {
      int col = wid * 10 + t;
      float u = pb1 + w0 * prx[col] + w1 * pry[col] + w2 * prz[col];
      float tv = fmaxf(u * sc + sh, 0.f);
      *(_Float16*)(t1b + ((col * 128 + ph * 2) ^ ((col & 7) << 4))) = (_Float16)tv;
    }
  }
  __syncthreads();

  // P3a: pe = pm_w2 @ t1 (mt=wid, 2 ks, 3 nt) -> pe f32 [col][o] swz
  {
    f32x4_t pacc[3];
#pragma unroll
    for (int nt = 0; nt < 3; ++nt) pacc[nt] = f32x4_t{0.f, 0.f, 0.f, 0.f};
    const int mt = wid;
#pragma unroll
    for (int ks = 0; ks < 2; ++ks) {
      U4H8 a;
      a.u = ((const uint4*)((const unsigned*)(wf + OPWF)))[(mt * 2 + ks) * 64 + lane];
#pragma unroll
      for (int nt = 0; nt < 3; ++nt) {
        int kc = nt * 16 + (lane & 15);
        U4H8 bu;
        bu.u = *(const uint4*)(t1b + ((kc * 128 + (ks * 32 + ((lane >> 4) << 3)) * 2) ^ ((kc & 7) << 4)));
        pacc[nt] = mfma_16x16x32(a.h, bu.h, pacc[nt]);
      }
    }
    const int o0 = mt * 16 + ((lane >> 4) << 2);
    float4 pb2v = *(const float4*)(wf + OPB2 + o0);
#pragma unroll
    for (int nt = 0; nt < 3; ++nt) {
      int kc = nt * 16 + (lane & 15);
      float4 o;
      o.x = pacc[nt][0] + pb2v.x; o.y = pacc[nt][1] + pb2v.y;
      o.z = pacc[nt][2] + pb2v.z; o.w = pacc[nt][3] + pb2v.w;
      *(float4*)(peb + ((kc * 256 + o0 * 4) ^ ((kc & 7) << 4))) = o;
    }
  }
  __syncthreads();

  // P3b: fold pe into S (f16 swz) and sVal (f16)
  {
#pragma unroll
    for (int t = 0; t < 10; ++t) {
      int col = wid * 10 + t;
      float pe = *(const float*)(peb + ((col * 256 + lane * 4) ^ ((col & 7) << 4)));
      float sv = sreg[t] + pe;
      float vv = vreg[t] + pe;
      *(_Float16*)(svb + col * 128 + lane * 2) = (_Float16)vv;
      *(_Float16*)(Sb + ((col * 128 + lane * 2) ^ ((col & 7) << 4))) = (_Float16)sv;
    }
  }
  __syncthreads();

  // P4: h = relu(bn(am_w1 @ S)) (16 mt: wid*4+pass*2+m, 2 ks, 3 nt)
#pragma unroll
  for (int pass = 0; pass < 2; ++pass) {
    const int mt0 = wid * 4 + pass * 2;
    f32x4_t acc[2][3];
#pragma unroll
    for (int m = 0; m < 2; ++m)
#pragma unroll
      for (int nt = 0; nt < 3; ++nt) acc[m][nt] = f32x4_t{0.f, 0.f, 0.f, 0.f};
#pragma unroll
    for (int ks = 0; ks < 2; ++ks) {
      U4H8 bfr[3];
#pragma unroll
      for (int nt = 0; nt < 3; ++nt) {
        int kc = nt * 16 + (lane & 15);
        bfr[nt].u = *(const uint4*)(Sb + ((kc * 128 + (ks * 32 + ((lane >> 4) << 3)) * 2) ^ ((kc & 7) << 4)));
      }
#pragma unroll
      for (int m = 0; m < 2; ++m) {
        U4H8 a;
        a.u = ((const uint4*)((const unsigned*)(wf + OAWF)))[((mt0 + m) * 2 + ks) * 64 + lane];
#pragma unroll
        for (int nt = 0; nt < 3; ++nt)
          acc[m][nt] = mfma_16x16x32(a.h, bfr[nt].h, acc[m][nt]);
      }
    }
#pragma unroll
    for (int m = 0; m < 2; ++m) {
      const int c0 = (mt0 + m) * 16 + ((lane >> 4) << 2);
      float4 ab1 = *(const float4*)(wf + OAB1 + c0);
      float4 asc = *(const float4*)(wf + OASC + c0);
      float4 ash = *(const float4*)(wf + OASH + c0);
#pragma unroll
      for (int nt = 0; nt < 3; ++nt) {
        int kc = nt * 16 + (lane & 15);
        float h0 = fmaxf((acc[m][nt][0] + ab1.x) * asc.x + ash.x, 0.f);
        float h1 = fmaxf((acc[m][nt][1] + ab1.y) * asc.y + ash.y, 0.f);
        float h2 = fmaxf((acc[m][nt][2] + ab1.z) * asc.z + ash.z, 0.f);
        float h3 = fmaxf((acc[m][nt][3] + ab1.w) * asc.w + ash.w, 0.f);
        uint2 p;
        p.x = pkh2(h0, h1);
        p.y = pkh2(h2, h3);
        *(uint2*)(hb + ((kc * 512 + c0 * 2) ^ ((kc & 7) << 4))) = p;
      }
    }
  }
  __syncthreads();

  // P5: lg = wt @ h (8 mt: wid*2+m, 8 ks, 3 nt)
  {
    f32x4_t acc5[2][3];
#pragma unroll
    for (int m = 0; m < 2; ++m)
#pragma unroll
      for (int nt = 0; nt < 3; ++nt) acc5[m][nt] = f32x4_t{0.f, 0.f, 0.f, 0.f};
#pragma unroll
    for (int ks = 0; ks < 8; ++ks) {
      U4H8 bfr[3];
#pragma unroll
      for (int nt = 0; nt < 3; ++nt) {
        int kc = nt * 16 + (lane & 15);
        bfr[nt].u = *(const uint4*)(hb + ((kc * 512 + (ks * 32 + ((lane >> 4) << 3)) * 2) ^ ((kc & 7) << 4)));
      }
#pragma unroll
      for (int m = 0; m < 2; ++m) {
        U4H8 a;
        a.u = ((const uint4*)((const unsigned*)(wf + OWTF)))[((wid * 2 + m) * 8 + ks) * 64 + lane];
#pragma unroll
        for (int nt = 0; nt < 3; ++nt)
          acc5[m][nt] = mfma_16x16x32(a.h, bfr[nt].h, acc5[m][nt]);
      }
    }
    __syncthreads();  // all h reads done before lg overlays the region
#pragma unroll
    for (int m = 0; m < 2; ++m) {
      const int or0 = (wid * 2 + m) * 16 + ((lane >> 4) << 2);
#pragma unroll
      for (int nt = 0; nt < 3; ++nt) {
        int kc = nt * 16 + (lane & 15);
        if (kc < 40) {
#pragma unroll
          for (int r = 0; r < 4; ++r) lg[kc * 129 + or0 + r] = acc5[m][nt][r];
        }
      }
    }
  }
  __syncthreads();

  // P6: softmax over k + aggregate; all 256 threads (qsel = tid>>7)
  {
    const int qsel = tid >> 7, orr = tid & 127, o = orr >> 1;
    float l[20];
#pragma unroll
    for (int kk = 0; kk < 20; ++kk) l[kk] = lg[(qsel * 20 + kk) * 129 + orr];
    float bt = wf[OABT + o];
    float m = -3.4e38f;
#pragma unroll
    for (int kk = 0; kk < 20; ++kk) { l[kk] += bt; m = fmaxf(m, l[kk]); }
    float s = 0.f;
#pragma unroll
    for (int kk = 0; kk < 20; ++kk) { l[kk] = expf(l[kk] - m); s += l[kk]; }
    float inv = 1.f / s;
    float a = 0.f;
#pragma unroll
    for (int kk = 0; kk < 20; ++kk)
      a += l[kk] * (float)(*(const _Float16*)(svb + (qsel * 20 + kk) * 128 + o * 2));
    aggs[qsel * 128 + orr] = a * inv;
  }
  __syncthreads();

  // P7: y = we @ agg + be + iden; native we [co][o], float4; both queries
  {
    const int co = tid & 127, r = tid >> 7;
    float y0 = wf[OBE + co], y1 = y0;
    const float* w = wf + OWET + co * 64;
#pragma unroll 4
    for (int o4 = 0; o4 < 16; ++o4) {
      float4 w4 = *(const float4*)(w + o4 * 4);
      const float wv[4] = {w4.x, w4.y, w4.z, w4.w};
#pragma unroll
      for (int j = 0; j < 4; ++j) {
        int oi = o4 * 4 + j;
        y0 += wv[j] * aggs[oi * 2 + r];
        y1 += wv[j] * aggs[128 + oi * 2 + r];
      }
    }
    float id0 = idenb[((size_t)b * N_ + n0) * 128 + co];
    float id1 = idenb[((size_t)b * N_ + n0 + 1) * 128 + co];
    size_t obase = ((size_t)b * 128 + co) * (size_t)(2 * N_);
    out[obase + 2 * n0 + r] = y0 + id0;
    out[obase + 2 * n0 + 2 + r] = y1 + id1;
  }
}

extern "C" void kernel_launch(void* const* d_in, const int* in_sizes, int n_in,
                              void* d_out, int out_size, void* d_ws, size_t ws_size,
                              hipStream_t stream) {
  (void)in_sizes; (void)n_in; (void)out_size; (void)ws_size;
  InPtrs ip;
  for (int i = 0; i < 38; ++i) ip.p[i] = (const float*)d_in[i];
  char* ws = (char*)d_ws;
  float* wf    = (float*)(ws + OFFB_WF);
  int*   idxb  = (int*)(ws + OFFB_IDX);
  float* qb    = (float*)(ws + OFFB_Q);
  float* kb    = (float*)(ws + OFFB_K);
  float* ubuf  = (float*)(ws + OFFB_U);
  float* vbuf  = (float*)(ws + OFFB_V);
  float* idenb = (float*)(ws + OFFB_IDEN);

  k_prep<<<dim3(256), dim3(256), 0, stream>>>(ip, wf);
  k_mv<<<dim3(64, 8), dim3(256), 0, stream>>>(wf, ip.p[1], ip.p[2], ip.p[3],
                                              vbuf, idenb, qb, kb, ubuf);
  k_knn<<<dim3(B_ * N_), dim3(256), 0, stream>>>(ip.p[0], idxb);
  k_attn<<<dim3(B_ * N_ / 2), dim3(256), 0, stream>>>(wf, qb, kb, vbuf, ubuf, idenb, idxb,
                                                      ip.p[0], (float*)d_out);
}